// Round 3
// baseline (1780.944 us; speedup 1.0000x reference)
//
#include <hip/hip_runtime.h>

typedef unsigned short u16;
typedef __attribute__((ext_vector_type(8))) short bf8_t;    // 8 x bf16 (4 VGPRs)
typedef __attribute__((ext_vector_type(4))) float f4_t;     // 4 x f32
typedef __attribute__((ext_vector_type(4))) unsigned short u16x4;

__device__ __forceinline__ float b2f(u16 h) {
  union { unsigned u; float f; } v; v.u = ((unsigned)h) << 16; return v.f;
}
__device__ __forceinline__ u16 f2b(float f) {
  union { float f; unsigned u; } v; v.f = f;
  unsigned u = v.u;
  u += 0x7fffu + ((u >> 16) & 1u);   // round-nearest-even
  return (u16)(u >> 16);
}

#define AS1C(p) ((const __attribute__((address_space(1))) void*)(p))
#define AS3(p)  ((__attribute__((address_space(3))) void*)(p))

// vectorized f32 -> bf16 convert (n multiple of 4)
__global__ __launch_bounds__(256)
void cvt_bf16(const float* __restrict__ s, u16* __restrict__ d, int n4)
{
  int i = blockIdx.x * 256 + threadIdx.x;
  if (i >= n4) return;
  f4_t v = *(const f4_t*)(s + (size_t)i * 4);
  u16x4 o;
#pragma unroll
  for (int j = 0; j < 4; ++j) o[j] = f2b(v[j]);
  *(u16x4*)(d + (size_t)i * 4) = o;
}

// Stage one 128x32 bf16 tile (8 KB) into LDS: 2 x 1KB chunks per wave.
// LDS layout packed [128][32] (row stride 64 B) — required by global_load_lds
// (wave-uniform base + lane*16; lane i -> row chunk*16 + i/4, col (i%4)*8).
__device__ __forceinline__ void stage_wave(const u16* g, int ld, int row0, int rowmax,
                                           int k0, u16* lds, int wid, int lane) {
#pragma unroll
  for (int c = 0; c < 2; ++c) {
    int chunk = wid * 2 + c;
    int r = row0 + chunk * 16 + (lane >> 2);
    if (r > rowmax) r = rowmax;                       // clamp (results discarded later)
    const u16* gp = g + (size_t)r * ld + k0 + (lane & 3) * 8;
    __builtin_amdgcn_global_load_lds(AS1C(gp), AS3(lds + chunk * 512), 16, 0, 0);
  }
}

// C = A * Bt^T : A[M,K] bf16 row-major (lda), Bt[N,K] bf16 row-major (ldb).
// EPI 0: in_proj  -> o16: n<2048 -> xi[m*2048+n]; else z at o16+8388608
// EPI 1: x_proj   -> o16[m*96+n] (n<Nact=96), bf16
// EPI 2: dt_proj  -> o16[m*2048+n] = bf16(softplus(acc + biasf[n]))
// EPI 3: out_proj -> of32[m*1024+n]
template<int EPI>
__global__ __launch_bounds__(256)
void gemm_bt(const u16* __restrict__ A, int lda,
             const u16* __restrict__ Bt, int ldb,
             int K, int Nact,
             u16* __restrict__ o16, float* __restrict__ of32,
             const float* __restrict__ biasf)
{
  __shared__ u16 lsA[128 * 32];
  __shared__ u16 lsB[128 * 32];
  const int tid = threadIdx.x;
  const int wid = tid >> 6, lane = tid & 63;
  const int wm = wid >> 1, wn = wid & 1;          // 2x2 wave grid, 64x64 each
  const int lrow = lane & 15;
  const int lk = (lane >> 4) * 8;
  const int m0 = blockIdx.y * 128;
  const int n0 = blockIdx.x * 128;

  f4_t acc[4][4];
#pragma unroll
  for (int i = 0; i < 4; ++i)
#pragma unroll
    for (int j = 0; j < 4; ++j) acc[i][j] = {0.f, 0.f, 0.f, 0.f};

  for (int kt = 0; kt < K; kt += 32) {
    stage_wave(A,  lda, m0, 0x3fffffff, kt, lsA, wid, lane);
    stage_wave(Bt, ldb, n0, Nact - 1,   kt, lsB, wid, lane);
    __syncthreads();
    bf8_t af[4], bfr[4];
#pragma unroll
    for (int mi = 0; mi < 4; ++mi)
      af[mi] = *(const bf8_t*)&lsA[(wm * 64 + mi * 16 + lrow) * 32 + lk];
#pragma unroll
    for (int ni = 0; ni < 4; ++ni)
      bfr[ni] = *(const bf8_t*)&lsB[(wn * 64 + ni * 16 + lrow) * 32 + lk];
#pragma unroll
    for (int mi = 0; mi < 4; ++mi)
#pragma unroll
      for (int ni = 0; ni < 4; ++ni)
        acc[mi][ni] = __builtin_amdgcn_mfma_f32_16x16x32_bf16(af[mi], bfr[ni], acc[mi][ni], 0, 0, 0);
    __syncthreads();
  }

  const int rq = (lane >> 4) * 4;                  // C/D: row=(lane>>4)*4+r, col=lane&15
#pragma unroll
  for (int mi = 0; mi < 4; ++mi) {
#pragma unroll
    for (int ni = 0; ni < 4; ++ni) {
#pragma unroll
      for (int r = 0; r < 4; ++r) {
        int m = m0 + wm * 64 + mi * 16 + rq + r;
        int n = n0 + wn * 64 + ni * 16 + lrow;
        float v = acc[mi][ni][r];
        if (EPI == 0) {
          if (n < 2048) o16[(size_t)m * 2048 + n] = f2b(v);
          else          o16[(size_t)8388608 + (size_t)m * 2048 + (n - 2048)] = f2b(v);
        } else if (EPI == 1) {
          if (n < Nact) o16[(size_t)m * 96 + n] = f2b(v);
        } else if (EPI == 2) {
          float t = v + biasf[n];
          float sp = (t > 20.f) ? t : log1pf(__expf(t));
          o16[(size_t)m * 2048 + n] = f2b(sp);
        } else {
          of32[(size_t)m * 1024 + n] = v;
        }
      }
    }
  }
}

// causal depthwise conv1d (window 4) + bias + silu; bf16 in (xi), f32 weights, bf16 out
__global__ __launch_bounds__(256)
void conv_silu(const u16* __restrict__ xib, const float* __restrict__ cw,
               const float* __restrict__ cb, u16* __restrict__ ub)
{
  int idx = blockIdx.x * 256 + threadIdx.x;   // [b*L + l][c], c fastest
  int c = idx & 2047;
  int i = idx >> 11;
  int l = i & 2047;
  float acc = cb[c];
  float w0 = cw[c * 4 + 0], w1 = cw[c * 4 + 1];
  float w2 = cw[c * 4 + 2], w3 = cw[c * 4 + 3];
  const u16* xc = xib + (size_t)i * 2048 + c;
  if (l >= 3) {
    acc += w0 * b2f(xc[-3 * 2048]) + w1 * b2f(xc[-2 * 2048])
         + w2 * b2f(xc[-2048]) + w3 * b2f(xc[0]);
  } else {
    acc += w3 * b2f(xc[0]);
    if (l >= 1) acc += w2 * b2f(xc[-2048]);
    if (l >= 2) acc += w1 * b2f(xc[-2 * 2048]);
  }
  float s = acc / (1.f + __expf(-acc));
  ub[idx] = f2b(s);
}

// selective scan: 16 lanes per (b,d) chain, one state n per lane.
// fused: +u*D skip, *silu(z) gate. Reads z from zy, writes y into the SAME
// slot (read-before-write within the owning lane -> safe aliasing).
__global__ __launch_bounds__(256)
void scan_kernel(const u16* __restrict__ delta_bf, const u16* __restrict__ ub,
                 const u16* __restrict__ xdbl_bf, u16* __restrict__ zy,
                 const float* __restrict__ alog, const float* __restrict__ Dw)
{
  int blk = blockIdx.x;                // 256 blocks: [batch][d-group of 16]
  int batch = blk >> 7;
  int d0 = (blk & 127) * 16;
  int tid = threadIdx.x;
  int wid = tid >> 6, lane = tid & 63;
  int n = lane & 15, g = lane >> 4;
  int d = d0 + wid * 4 + g;
  float Aval = -__expf(alog[d * 16 + n]);
  float Dv = Dw[d];
  float h = 0.f;
  size_t base = (size_t)batch * 2048;
  for (int l = 0; l < 2048; ++l) {
    size_t row = base + l;
    float dlt = b2f(delta_bf[row * 2048 + d]);
    float uv  = b2f(ub[row * 2048 + d]);
    float Bv  = b2f(xdbl_bf[row * 96 + 64 + n]);
    float Cv  = b2f(xdbl_bf[row * 96 + 80 + n]);
    float a = __expf(dlt * Aval);
    h = a * h + (dlt * uv) * Bv;
    float y = h * Cv;
    y += __shfl_xor(y, 1, 16);
    y += __shfl_xor(y, 2, 16);
    y += __shfl_xor(y, 4, 16);
    y += __shfl_xor(y, 8, 16);
    if (n == 0) {
      float zv = b2f(zy[row * 2048 + d]);
      float o = (y + Dv * uv) * (zv / (1.f + __expf(-zv)));
      zy[row * 2048 + d] = f2b(o);
    }
  }
}

// residual + LayerNorm, f32 in/out. One block (256 thr) per row of 1024.
__global__ __launch_bounds__(256)
void ln_kernel(const float* __restrict__ hp, const float* __restrict__ xin,
               const float* __restrict__ lnw, const float* __restrict__ lnb,
               float* __restrict__ outp)
{
  __shared__ float ssum[4], ssq[4];
  int row = blockIdx.x, t = threadIdx.x;
  const float* hr = hp + (size_t)row * 1024;
  const float* xr = xin + (size_t)row * 1024;
  f4_t hv = *(const f4_t*)(hr + t * 4);
  f4_t xv = *(const f4_t*)(xr + t * 4);
  float v[4], s = 0.f, q = 0.f;
#pragma unroll
  for (int j = 0; j < 4; ++j) { v[j] = hv[j] + xv[j]; s += v[j]; q += v[j] * v[j]; }
#pragma unroll
  for (int m = 32; m; m >>= 1) { s += __shfl_xor(s, m, 64); q += __shfl_xor(q, m, 64); }
  int wv = t >> 6;
  if ((t & 63) == 0) { ssum[wv] = s; ssq[wv] = q; }
  __syncthreads();
  s = ssum[0] + ssum[1] + ssum[2] + ssum[3];
  q = ssq[0] + ssq[1] + ssq[2] + ssq[3];
  float mu = s * (1.f / 1024.f);
  float var = q * (1.f / 1024.f) - mu * mu;
  float rs = rsqrtf(var + 1e-5f);
  f4_t o;
#pragma unroll
  for (int j = 0; j < 4; ++j)
    o[j] = (v[j] - mu) * rs * lnw[t * 4 + j] + lnb[t * 4 + j];
  *(f4_t*)(outp + (size_t)row * 1024 + t * 4) = o;
}

extern "C" void kernel_launch(void* const* d_in, const int* in_sizes, int n_in,
                              void* d_out, int out_size, void* d_ws, size_t ws_size,
                              hipStream_t stream)
{
  const float* x      = (const float*)d_in[0];   // [2,2048,1024]
  const float* inW    = (const float*)d_in[1];   // [4096,1024]
  const float* convW  = (const float*)d_in[2];   // [2048,1,4]
  const float* convB  = (const float*)d_in[3];   // [2048]
  const float* xprojW = (const float*)d_in[4];   // [96,2048]
  const float* dtW    = (const float*)d_in[5];   // [2048,64]
  const float* dtB    = (const float*)d_in[6];   // [2048]
  const float* alog   = (const float*)d_in[7];   // [2048,16]
  const float* Dw     = (const float*)d_in[8];   // [2048]
  const float* outW   = (const float*)d_in[9];   // [1024,2048]
  const float* lnw    = (const float*)d_in[10];  // [1024]
  const float* lnb    = (const float*)d_in[11];  // [1024]
  float* out = (float*)d_out;                    // [2,2048,1024] f32

  // Workspace layout (total ~53.4 MB):
  //  [0,16M):    xi bf16 [4096,2048] -> delta bf16 -> hproj f32 [4096,1024]
  //  [16M,32M):  z bf16 [4096,2048]  -> y bf16 (scan overwrites in place)
  //  [32M,48M):  xb bf16 (8M) + inWb bf16 (8M)  -> u bf16 [4096,2048] (after gemm0)
  //  [48M,48.75M):   xdbl bf16 [4096,96]
  //  [48.75M,53.4M): xprojWb (384K) | dtWb (256K) | outWb (4M)
  char* ws = (char*)d_ws;
  u16*   xiz    = (u16*)(ws);
  u16*   zy     = xiz + 8388608;
  u16*   xb     = (u16*)(ws + 33554432);
  u16*   inWb   = xb + 4194304;
  u16*   u_bf   = (u16*)(ws + 33554432);          // overwrites xb/inWb after gemm0
  u16*   xdbl   = (u16*)(ws + 50331648);
  u16*   xprojWb= (u16*)(ws + 51118080);
  u16*   dtWb   = (u16*)(ws + 51511296);
  u16*   outWb  = (u16*)(ws + 51773440);
  u16*   delta  = xiz;                            // overwrites dead xi
  float* hproj  = (float*)(ws);                   // overwrites dead delta

  dim3 blk(256);
  // f32 -> bf16 conversions
  cvt_bf16<<<4096, blk, 0, stream>>>(x,      xb,      1048576);
  cvt_bf16<<<4096, blk, 0, stream>>>(inW,    inWb,    1048576);
  cvt_bf16<<<192,  blk, 0, stream>>>(xprojW, xprojWb, 49152);
  cvt_bf16<<<128,  blk, 0, stream>>>(dtW,    dtWb,    32768);
  cvt_bf16<<<2048, blk, 0, stream>>>(outW,   outWb,   524288);

  // in_proj: [4096,1024] x [4096,1024]^T -> xi | z (bf16)
  gemm_bt<0><<<dim3(32, 32), blk, 0, stream>>>(xb, 1024, inWb, 1024, 1024, 4096, xiz, nullptr, nullptr);
  // depthwise causal conv + silu -> u (bf16; overwrites xb/inWb)
  conv_silu<<<32768, blk, 0, stream>>>(xiz, convW, convB, u_bf);
  // x_proj: [4096,2048] x [96,2048]^T -> x_dbl (bf16)
  gemm_bt<1><<<dim3(1, 32), blk, 0, stream>>>(u_bf, 2048, xprojWb, 2048, 2048, 96, xdbl, nullptr, nullptr);
  // dt_proj + softplus -> delta (bf16, overwrites xi); A = x_dbl[:,0:64] strided lda=96
  gemm_bt<2><<<dim3(16, 32), blk, 0, stream>>>(xdbl, 96, dtWb, 64, 64, 2048, delta, nullptr, dtB);
  // selective scan + skip + gate -> y (bf16, in place over z)
  scan_kernel<<<256, blk, 0, stream>>>(delta, u_bf, xdbl, zy, alog, Dw);
  // out_proj: [4096,2048] x [1024,2048]^T -> hproj f32 (overwrites delta region)
  gemm_bt<3><<<dim3(8, 32), blk, 0, stream>>>(zy, 2048, outWb, 2048, 2048, 1024, nullptr, hproj, nullptr);
  // residual + LayerNorm -> f32 out
  ln_kernel<<<4096, blk, 0, stream>>>(hproj, x, lnw, lnb, out);
}

// Round 4
// 730.011 us; speedup vs baseline: 2.4396x; 2.4396x over previous
//
#include <hip/hip_runtime.h>

typedef unsigned short u16;
typedef __attribute__((ext_vector_type(8))) short bf8_t;    // 8 x bf16 (4 VGPRs)
typedef __attribute__((ext_vector_type(4))) float f4_t;     // 4 x f32
typedef __attribute__((ext_vector_type(4))) unsigned short u16x4;

__device__ __forceinline__ float b2f(u16 h) {
  union { unsigned u; float f; } v; v.u = ((unsigned)h) << 16; return v.f;
}
__device__ __forceinline__ u16 f2b(float f) {
  union { float f; unsigned u; } v; v.f = f;
  unsigned u = v.u;
  u += 0x7fffu + ((u >> 16) & 1u);   // round-nearest-even
  return (u16)(u >> 16);
}

#define AS1C(p) ((const __attribute__((address_space(1))) void*)(p))
#define AS3(p)  ((__attribute__((address_space(3))) void*)(p))

// vectorized f32 -> bf16 convert (n multiple of 4)
__global__ __launch_bounds__(256)
void cvt_bf16(const float* __restrict__ s, u16* __restrict__ d, int n4)
{
  int i = blockIdx.x * 256 + threadIdx.x;
  if (i >= n4) return;
  f4_t v = *(const f4_t*)(s + (size_t)i * 4);
  u16x4 o;
#pragma unroll
  for (int j = 0; j < 4; ++j) o[j] = f2b(v[j]);
  *(u16x4*)(d + (size_t)i * 4) = o;
}

// Stage one 128x32 bf16 tile (8 KB) into LDS: 2 x 1KB chunks per wave.
// LDS layout packed [128][32] (row stride 64 B) — required by global_load_lds
// (wave-uniform base + lane*16; lane i -> row chunk*16 + i/4, col (i%4)*8).
__device__ __forceinline__ void stage_wave(const u16* g, int ld, int row0, int rowmax,
                                           int k0, u16* lds, int wid, int lane) {
#pragma unroll
  for (int c = 0; c < 2; ++c) {
    int chunk = wid * 2 + c;
    int r = row0 + chunk * 16 + (lane >> 2);
    if (r > rowmax) r = rowmax;                       // clamp (results discarded later)
    const u16* gp = g + (size_t)r * ld + k0 + (lane & 3) * 8;
    __builtin_amdgcn_global_load_lds(AS1C(gp), AS3(lds + chunk * 512), 16, 0, 0);
  }
}

// C = A * Bt^T : A[M,K] bf16 row-major (lda), Bt[N,K] bf16 row-major (ldb).
// EPI 0: in_proj  -> o16: n<2048 -> xi[m*2048+n]; else z at o16+8388608
// EPI 1: x_proj   -> o16[m*96+n] (n<Nact=96), bf16
// EPI 2: dt_proj  -> o16[m*2048+n] = bf16(softplus(acc + biasf[n]))
// EPI 3: out_proj -> of32[m*1024+n]
template<int EPI>
__global__ __launch_bounds__(256)
void gemm_bt(const u16* __restrict__ A, int lda,
             const u16* __restrict__ Bt, int ldb,
             int K, int Nact,
             u16* __restrict__ o16, float* __restrict__ of32,
             const float* __restrict__ biasf)
{
  __shared__ u16 lsA[128 * 32];
  __shared__ u16 lsB[128 * 32];
  const int tid = threadIdx.x;
  const int wid = tid >> 6, lane = tid & 63;
  const int wm = wid >> 1, wn = wid & 1;          // 2x2 wave grid, 64x64 each
  const int lrow = lane & 15;
  const int lk = (lane >> 4) * 8;
  const int m0 = blockIdx.y * 128;
  const int n0 = blockIdx.x * 128;

  f4_t acc[4][4];
#pragma unroll
  for (int i = 0; i < 4; ++i)
#pragma unroll
    for (int j = 0; j < 4; ++j) acc[i][j] = {0.f, 0.f, 0.f, 0.f};

  for (int kt = 0; kt < K; kt += 32) {
    stage_wave(A,  lda, m0, 0x3fffffff, kt, lsA, wid, lane);
    stage_wave(Bt, ldb, n0, Nact - 1,   kt, lsB, wid, lane);
    __syncthreads();
    bf8_t af[4], bfr[4];
#pragma unroll
    for (int mi = 0; mi < 4; ++mi)
      af[mi] = *(const bf8_t*)&lsA[(wm * 64 + mi * 16 + lrow) * 32 + lk];
#pragma unroll
    for (int ni = 0; ni < 4; ++ni)
      bfr[ni] = *(const bf8_t*)&lsB[(wn * 64 + ni * 16 + lrow) * 32 + lk];
#pragma unroll
    for (int mi = 0; mi < 4; ++mi)
#pragma unroll
      for (int ni = 0; ni < 4; ++ni)
        acc[mi][ni] = __builtin_amdgcn_mfma_f32_16x16x32_bf16(af[mi], bfr[ni], acc[mi][ni], 0, 0, 0);
    __syncthreads();
  }

  const int rq = (lane >> 4) * 4;                  // C/D: row=(lane>>4)*4+r, col=lane&15
#pragma unroll
  for (int mi = 0; mi < 4; ++mi) {
#pragma unroll
    for (int ni = 0; ni < 4; ++ni) {
#pragma unroll
      for (int r = 0; r < 4; ++r) {
        int m = m0 + wm * 64 + mi * 16 + rq + r;
        int n = n0 + wn * 64 + ni * 16 + lrow;
        float v = acc[mi][ni][r];
        if (EPI == 0) {
          if (n < 2048) o16[(size_t)m * 2048 + n] = f2b(v);
          else          o16[(size_t)8388608 + (size_t)m * 2048 + (n - 2048)] = f2b(v);
        } else if (EPI == 1) {
          if (n < Nact) o16[(size_t)m * 96 + n] = f2b(v);
        } else if (EPI == 2) {
          float t = v + biasf[n];
          float sp = (t > 20.f) ? t : log1pf(__expf(t));
          o16[(size_t)m * 2048 + n] = f2b(sp);
        } else {
          of32[(size_t)m * 1024 + n] = v;
        }
      }
    }
  }
}

// causal depthwise conv1d (window 4) + bias + silu; bf16 in (xi), f32 weights, bf16 out
__global__ __launch_bounds__(256)
void conv_silu(const u16* __restrict__ xib, const float* __restrict__ cw,
               const float* __restrict__ cb, u16* __restrict__ ub)
{
  int idx = blockIdx.x * 256 + threadIdx.x;   // [b*L + l][c], c fastest
  int c = idx & 2047;
  int i = idx >> 11;
  int l = i & 2047;
  float acc = cb[c];
  float w0 = cw[c * 4 + 0], w1 = cw[c * 4 + 1];
  float w2 = cw[c * 4 + 2], w3 = cw[c * 4 + 3];
  const u16* xc = xib + (size_t)i * 2048 + c;
  if (l >= 3) {
    acc += w0 * b2f(xc[-3 * 2048]) + w1 * b2f(xc[-2 * 2048])
         + w2 * b2f(xc[-2048]) + w3 * b2f(xc[0]);
  } else {
    acc += w3 * b2f(xc[0]);
    if (l >= 1) acc += w2 * b2f(xc[-2048]);
    if (l >= 2) acc += w1 * b2f(xc[-2 * 2048]);
  }
  float s = acc / (1.f + __expf(-acc));
  ub[idx] = f2b(s);
}

// Chunk-parallel selective scan. One block per (batch, d): 256 threads =
// 16 chunks (of 128 steps) x 16 states n. Exact linear-recurrence
// decomposition: pass1 computes per-chunk (P = prod a, q = from-zero state),
// 16-step LDS combine yields each chunk's incoming h, pass2 re-scans and
// emits y fused with D-skip and silu(z) gate (in place over z).
__global__ __launch_bounds__(256)
void scan_chunked(const u16* __restrict__ delta_bf, const u16* __restrict__ ub,
                  const u16* __restrict__ xdbl_bf, u16* __restrict__ zy,
                  const float* __restrict__ alog, const float* __restrict__ Dw)
{
  __shared__ float sP[16][16], sQ[16][16], sH[16][16];
  int blk = blockIdx.x;                // 4096 blocks: batch*2048 + d
  int batch = blk >> 11;
  int d = blk & 2047;
  int tid = threadIdx.x;
  int chunk = tid >> 4, n = tid & 15;
  float Aval = -__expf(alog[d * 16 + n]);
  float Dv = Dw[d];
  size_t base = (size_t)batch * 2048 + (size_t)chunk * 128;

  // pass 1: chunk transition (P, q) from h=0
  float P = 1.f, q = 0.f;
  for (int i = 0; i < 128; ++i) {
    size_t row = base + i;
    float dlt = b2f(delta_bf[row * 2048 + d]);
    float uv  = b2f(ub[row * 2048 + d]);
    float Bv  = b2f(xdbl_bf[row * 96 + 64 + n]);
    float a = __expf(dlt * Aval);
    q = a * q + (dlt * uv) * Bv;
    P *= a;
  }
  sP[chunk][n] = P;
  sQ[chunk][n] = q;
  __syncthreads();

  // combine: exclusive prefix over 16 chunks (16 lanes, serial in c)
  if (tid < 16) {
    float H = 0.f;
    for (int c = 0; c < 16; ++c) {
      sH[c][tid] = H;
      H = sP[c][tid] * H + sQ[c][tid];
    }
  }
  __syncthreads();

  // pass 2: re-scan with correct incoming state, emit gated y
  float h = sH[chunk][n];
  for (int i = 0; i < 128; ++i) {
    size_t row = base + i;
    float dlt = b2f(delta_bf[row * 2048 + d]);
    float uv  = b2f(ub[row * 2048 + d]);
    float Bv  = b2f(xdbl_bf[row * 96 + 64 + n]);
    float Cv  = b2f(xdbl_bf[row * 96 + 80 + n]);
    float a = __expf(dlt * Aval);
    h = a * h + (dlt * uv) * Bv;
    float y = h * Cv;
    y += __shfl_xor(y, 1, 16);
    y += __shfl_xor(y, 2, 16);
    y += __shfl_xor(y, 4, 16);
    y += __shfl_xor(y, 8, 16);
    if (n == 0) {
      float zv = b2f(zy[row * 2048 + d]);
      float o = (y + Dv * uv) * (zv / (1.f + __expf(-zv)));
      zy[row * 2048 + d] = f2b(o);
    }
  }
}

// residual + LayerNorm, f32 in/out. One block (256 thr) per row of 1024.
__global__ __launch_bounds__(256)
void ln_kernel(const float* __restrict__ hp, const float* __restrict__ xin,
               const float* __restrict__ lnw, const float* __restrict__ lnb,
               float* __restrict__ outp)
{
  __shared__ float ssum[4], ssq[4];
  int row = blockIdx.x, t = threadIdx.x;
  const float* hr = hp + (size_t)row * 1024;
  const float* xr = xin + (size_t)row * 1024;
  f4_t hv = *(const f4_t*)(hr + t * 4);
  f4_t xv = *(const f4_t*)(xr + t * 4);
  float v[4], s = 0.f, q = 0.f;
#pragma unroll
  for (int j = 0; j < 4; ++j) { v[j] = hv[j] + xv[j]; s += v[j]; q += v[j] * v[j]; }
#pragma unroll
  for (int m = 32; m; m >>= 1) { s += __shfl_xor(s, m, 64); q += __shfl_xor(q, m, 64); }
  int wv = t >> 6;
  if ((t & 63) == 0) { ssum[wv] = s; ssq[wv] = q; }
  __syncthreads();
  s = ssum[0] + ssum[1] + ssum[2] + ssum[3];
  q = ssq[0] + ssq[1] + ssq[2] + ssq[3];
  float mu = s * (1.f / 1024.f);
  float var = q * (1.f / 1024.f) - mu * mu;
  float rs = rsqrtf(var + 1e-5f);
  f4_t o;
#pragma unroll
  for (int j = 0; j < 4; ++j)
    o[j] = (v[j] - mu) * rs * lnw[t * 4 + j] + lnb[t * 4 + j];
  *(f4_t*)(outp + (size_t)row * 1024 + t * 4) = o;
}

extern "C" void kernel_launch(void* const* d_in, const int* in_sizes, int n_in,
                              void* d_out, int out_size, void* d_ws, size_t ws_size,
                              hipStream_t stream)
{
  const float* x      = (const float*)d_in[0];   // [2,2048,1024]
  const float* inW    = (const float*)d_in[1];   // [4096,1024]
  const float* convW  = (const float*)d_in[2];   // [2048,1,4]
  const float* convB  = (const float*)d_in[3];   // [2048]
  const float* xprojW = (const float*)d_in[4];   // [96,2048]
  const float* dtW    = (const float*)d_in[5];   // [2048,64]
  const float* dtB    = (const float*)d_in[6];   // [2048]
  const float* alog   = (const float*)d_in[7];   // [2048,16]
  const float* Dw     = (const float*)d_in[8];   // [2048]
  const float* outW   = (const float*)d_in[9];   // [1024,2048]
  const float* lnw    = (const float*)d_in[10];  // [1024]
  const float* lnb    = (const float*)d_in[11];  // [1024]
  float* out = (float*)d_out;                    // [2,2048,1024] f32

  // Workspace layout (total ~53.4 MB):
  //  [0,16M):    xi bf16 [4096,2048] -> delta bf16 -> hproj f32 [4096,1024]
  //  [16M,32M):  z bf16 [4096,2048]  -> y bf16 (scan overwrites in place)
  //  [32M,48M):  xb bf16 (8M) + inWb bf16 (8M)  -> u bf16 [4096,2048] (after gemm0)
  //  [48M,48.75M):   xdbl bf16 [4096,96]
  //  [48.75M,53.4M): xprojWb (384K) | dtWb (256K) | outWb (4M)
  char* ws = (char*)d_ws;
  u16*   xiz    = (u16*)(ws);
  u16*   zy     = xiz + 8388608;
  u16*   xb     = (u16*)(ws + 33554432);
  u16*   inWb   = xb + 4194304;
  u16*   u_bf   = (u16*)(ws + 33554432);          // overwrites xb/inWb after gemm0
  u16*   xdbl   = (u16*)(ws + 50331648);
  u16*   xprojWb= (u16*)(ws + 51118080);
  u16*   dtWb   = (u16*)(ws + 51511296);
  u16*   outWb  = (u16*)(ws + 51773440);
  u16*   delta  = xiz;                            // overwrites dead xi
  float* hproj  = (float*)(ws);                   // overwrites dead delta

  dim3 blk(256);
  // f32 -> bf16 conversions
  cvt_bf16<<<4096, blk, 0, stream>>>(x,      xb,      1048576);
  cvt_bf16<<<4096, blk, 0, stream>>>(inW,    inWb,    1048576);
  cvt_bf16<<<192,  blk, 0, stream>>>(xprojW, xprojWb, 49152);
  cvt_bf16<<<128,  blk, 0, stream>>>(dtW,    dtWb,    32768);
  cvt_bf16<<<2048, blk, 0, stream>>>(outW,   outWb,   524288);

  // in_proj: [4096,1024] x [4096,1024]^T -> xi | z (bf16)
  gemm_bt<0><<<dim3(32, 32), blk, 0, stream>>>(xb, 1024, inWb, 1024, 1024, 4096, xiz, nullptr, nullptr);
  // depthwise causal conv + silu -> u (bf16; overwrites xb/inWb)
  conv_silu<<<32768, blk, 0, stream>>>(xiz, convW, convB, u_bf);
  // x_proj: [4096,2048] x [96,2048]^T -> x_dbl (bf16)
  gemm_bt<1><<<dim3(1, 32), blk, 0, stream>>>(u_bf, 2048, xprojWb, 2048, 2048, 96, xdbl, nullptr, nullptr);
  // dt_proj + softplus -> delta (bf16, overwrites xi); A = x_dbl[:,0:64] strided lda=96
  gemm_bt<2><<<dim3(16, 32), blk, 0, stream>>>(xdbl, 96, dtWb, 64, 64, 2048, delta, nullptr, dtB);
  // chunk-parallel selective scan + skip + gate -> y (bf16, in place over z)
  scan_chunked<<<4096, blk, 0, stream>>>(delta, u_bf, xdbl, zy, alog, Dw);
  // out_proj: [4096,2048] x [1024,2048]^T -> hproj f32 (overwrites delta region)
  gemm_bt<3><<<dim3(8, 32), blk, 0, stream>>>(zy, 2048, outWb, 2048, 2048, 1024, nullptr, hproj, nullptr);
  // residual + LayerNorm -> f32 out
  ln_kernel<<<4096, blk, 0, stream>>>(hproj, x, lnw, lnb, out);
}

// Round 6
// 425.201 us; speedup vs baseline: 4.1885x; 1.7169x over previous
//
#include <hip/hip_runtime.h>

typedef unsigned short u16;
typedef __attribute__((ext_vector_type(8))) short bf8_t;    // 8 x bf16 (4 VGPRs)
typedef __attribute__((ext_vector_type(4))) float f4_t;     // 4 x f32
typedef __attribute__((ext_vector_type(4))) unsigned short u16x4;

__device__ __forceinline__ float b2f(u16 h) {
  union { unsigned u; float f; } v; v.u = ((unsigned)h) << 16; return v.f;
}
__device__ __forceinline__ u16 f2b(float f) {
  union { float f; unsigned u; } v; v.f = f;
  unsigned u = v.u;
  u += 0x7fffu + ((u >> 16) & 1u);   // round-nearest-even
  return (u16)(u >> 16);
}

#define AS1C(p) ((const __attribute__((address_space(1))) void*)(p))
#define AS3(p)  ((__attribute__((address_space(3))) void*)(p))

// vectorized f32 -> bf16 convert (n multiple of 4)
__global__ __launch_bounds__(256)
void cvt_bf16(const float* __restrict__ s, u16* __restrict__ d, int n4)
{
  int i = blockIdx.x * 256 + threadIdx.x;
  if (i >= n4) return;
  f4_t v = *(const f4_t*)(s + (size_t)i * 4);
  u16x4 o;
#pragma unroll
  for (int j = 0; j < 4; ++j) o[j] = f2b(v[j]);
  *(u16x4*)(d + (size_t)i * 4) = o;
}

// Stage one 128x32 bf16 tile (8 KB) into LDS: 2 x 1KB chunks per wave.
__device__ __forceinline__ void stage_wave(const u16* g, int ld, int row0, int rowmax,
                                           int k0, u16* lds, int wid, int lane) {
#pragma unroll
  for (int c = 0; c < 2; ++c) {
    int chunk = wid * 2 + c;
    int r = row0 + chunk * 16 + (lane >> 2);
    if (r > rowmax) r = rowmax;                       // clamp (results discarded later)
    const u16* gp = g + (size_t)r * ld + k0 + (lane & 3) * 8;
    __builtin_amdgcn_global_load_lds(AS1C(gp), AS3(lds + chunk * 512), 16, 0, 0);
  }
}

// C = A * Bt^T : A[M,K] bf16 row-major (lda), Bt[N,K] bf16 row-major (ldb).
// EPI 0: in_proj  -> o16: n<2048 -> xi[m*2048+n]; else z at o16+8388608
// EPI 1: x_proj   -> n<64: o16[m*64+n] bf16 (dtA); 64<=n<96: of32[m*32+(n-64)] (B/C packed f32)
// EPI 2: dt_proj  -> o16[m*2048+n] = bf16(softplus(acc + biasf[n]))
// EPI 3: out_proj -> of32[m*1024+n]
template<int EPI>
__global__ __launch_bounds__(256)
void gemm_bt(const u16* __restrict__ A, int lda,
             const u16* __restrict__ Bt, int ldb,
             int K, int Nact,
             u16* __restrict__ o16, float* __restrict__ of32,
             const float* __restrict__ biasf)
{
  __shared__ u16 lsA[128 * 32];
  __shared__ u16 lsB[128 * 32];
  const int tid = threadIdx.x;
  const int wid = tid >> 6, lane = tid & 63;
  const int wm = wid >> 1, wn = wid & 1;          // 2x2 wave grid, 64x64 each
  const int lrow = lane & 15;
  const int lk = (lane >> 4) * 8;
  const int m0 = blockIdx.y * 128;
  const int n0 = blockIdx.x * 128;

  f4_t acc[4][4];
#pragma unroll
  for (int i = 0; i < 4; ++i)
#pragma unroll
    for (int j = 0; j < 4; ++j) acc[i][j] = {0.f, 0.f, 0.f, 0.f};

  for (int kt = 0; kt < K; kt += 32) {
    stage_wave(A,  lda, m0, 0x3fffffff, kt, lsA, wid, lane);
    stage_wave(Bt, ldb, n0, Nact - 1,   kt, lsB, wid, lane);
    __syncthreads();
    bf8_t af[4], bfr[4];
#pragma unroll
    for (int mi = 0; mi < 4; ++mi)
      af[mi] = *(const bf8_t*)&lsA[(wm * 64 + mi * 16 + lrow) * 32 + lk];
#pragma unroll
    for (int ni = 0; ni < 4; ++ni)
      bfr[ni] = *(const bf8_t*)&lsB[(wn * 64 + ni * 16 + lrow) * 32 + lk];
#pragma unroll
    for (int mi = 0; mi < 4; ++mi)
#pragma unroll
      for (int ni = 0; ni < 4; ++ni)
        acc[mi][ni] = __builtin_amdgcn_mfma_f32_16x16x32_bf16(af[mi], bfr[ni], acc[mi][ni], 0, 0, 0);
    __syncthreads();
  }

  const int rq = (lane >> 4) * 4;                  // C/D: row=(lane>>4)*4+r, col=lane&15
#pragma unroll
  for (int mi = 0; mi < 4; ++mi) {
#pragma unroll
    for (int ni = 0; ni < 4; ++ni) {
#pragma unroll
      for (int r = 0; r < 4; ++r) {
        int m = m0 + wm * 64 + mi * 16 + rq + r;
        int n = n0 + wn * 64 + ni * 16 + lrow;
        float v = acc[mi][ni][r];
        if (EPI == 0) {
          if (n < 2048) o16[(size_t)m * 2048 + n] = f2b(v);
          else          o16[(size_t)8388608 + (size_t)m * 2048 + (n - 2048)] = f2b(v);
        } else if (EPI == 1) {
          if (n < 64)      o16[(size_t)m * 64 + n] = f2b(v);
          else if (n < 96) of32[(size_t)m * 32 + (n - 64)] = v;
        } else if (EPI == 2) {
          float t = v + biasf[n];
          float sp = (t > 20.f) ? t : log1pf(__expf(t));
          o16[(size_t)m * 2048 + n] = f2b(sp);
        } else {
          of32[(size_t)m * 1024 + n] = v;
        }
      }
    }
  }
}

// causal depthwise conv1d (window 4) + bias + silu; bf16 in (xi), f32 weights, bf16 out
__global__ __launch_bounds__(256)
void conv_silu(const u16* __restrict__ xib, const float* __restrict__ cw,
               const float* __restrict__ cb, u16* __restrict__ ub)
{
  int idx = blockIdx.x * 256 + threadIdx.x;   // [b*L + l][c], c fastest
  int c = idx & 2047;
  int i = idx >> 11;
  int l = i & 2047;
  float acc = cb[c];
  float w0 = cw[c * 4 + 0], w1 = cw[c * 4 + 1];
  float w2 = cw[c * 4 + 2], w3 = cw[c * 4 + 3];
  const u16* xc = xib + (size_t)i * 2048 + c;
  if (l >= 3) {
    acc += w0 * b2f(xc[-3 * 2048]) + w1 * b2f(xc[-2 * 2048])
         + w2 * b2f(xc[-2048]) + w3 * b2f(xc[0]);
  } else {
    acc += w3 * b2f(xc[0]);
    if (l >= 1) acc += w2 * b2f(xc[-2048]);
    if (l >= 2) acc += w1 * b2f(xc[-2 * 2048]);
  }
  float s = acc / (1.f + __expf(-acc));
  ub[idx] = f2b(s);
}

// ---- chunk-parallel scan, d-in-lane layout. 32 chunks x 64 steps. ----
// S1: per (b,chunk,d) compute P[n]=prod a, q[n]=from-zero state, all 16 n in regs.
// Block = 256 threads = 256 consecutive d. Grid = ((b*32+c)*8+g), 512 blocks.
__global__ __launch_bounds__(256)
void scan_s1(const u16* __restrict__ delta_bf, const u16* __restrict__ ub,
             const float* __restrict__ bc, const float* __restrict__ alog,
             float* __restrict__ P, float* __restrict__ Q)
{
  int blk = blockIdx.x;
  int g = blk & 7, c = (blk >> 3) & 31, b = blk >> 8;
  int d = g * 256 + threadIdx.x;
  float Av[16];
#pragma unroll
  for (int nq = 0; nq < 4; ++nq) {
    f4_t al = *(const f4_t*)(alog + (size_t)d * 16 + nq * 4);
#pragma unroll
    for (int j = 0; j < 4; ++j) Av[nq * 4 + j] = -__expf(al[j]);
  }
  f4_t Pr[4], Qr[4];
#pragma unroll
  for (int nq = 0; nq < 4; ++nq) { Pr[nq] = {1.f,1.f,1.f,1.f}; Qr[nq] = {0.f,0.f,0.f,0.f}; }
  int row0 = b * 2048 + c * 64;
  for (int i = 0; i < 64; ++i) {
    size_t row = (size_t)(row0 + i);
    float dlt = b2f(delta_bf[row * 2048 + d]);
    float uv  = b2f(ub[row * 2048 + d]);
    const float* bp = bc + row * 32;
    f4_t Bv[4];
#pragma unroll
    for (int nq = 0; nq < 4; ++nq) Bv[nq] = *(const f4_t*)(bp + nq * 4);
    float du = dlt * uv;
#pragma unroll
    for (int n = 0; n < 16; ++n) {
      float a = __expf(dlt * Av[n]);
      Qr[n >> 2][n & 3] = a * Qr[n >> 2][n & 3] + du * Bv[n >> 2][n & 3];
      Pr[n >> 2][n & 3] *= a;
    }
  }
  size_t o = ((size_t)((b * 32 + c) * 2048 + d)) * 16;
#pragma unroll
  for (int nq = 0; nq < 4; ++nq) {
    *(f4_t*)(P + o + nq * 4) = Pr[nq];
    *(f4_t*)(Q + o + nq * 4) = Qr[nq];
  }
}

// S2: serial prefix over 32 chunks per (b,d,n); writes incoming-H into Q's slot.
__global__ __launch_bounds__(256)
void scan_comb(const float* __restrict__ P, float* __restrict__ Q)
{
  int idx = blockIdx.x * 256 + threadIdx.x;   // b*32768 + d*16+n
  int b = idx >> 15, dn = idx & 32767;
  size_t base = (size_t)b * 32 * 32768 + dn;
  float H = 0.f;
  for (int c = 0; c < 32; ++c) {
    size_t k = base + (size_t)c * 32768;
    float p = P[k], q = Q[k];
    Q[k] = H;
    H = p * H + q;
  }
}

// S3: re-scan with correct h_in; y = sum_n h*C in regs; fused D-skip + silu(z)
// gate; y overwrites z in place (coalesced bf16 stores).
__global__ __launch_bounds__(256)
void scan_s3(const u16* __restrict__ delta_bf, const u16* __restrict__ ub,
             const float* __restrict__ bc, const float* __restrict__ alog,
             const float* __restrict__ Q, const float* __restrict__ Dw,
             u16* __restrict__ zy)
{
  int blk = blockIdx.x;
  int g = blk & 7, c = (blk >> 3) & 31, b = blk >> 8;
  int d = g * 256 + threadIdx.x;
  float Av[16];
#pragma unroll
  for (int nq = 0; nq < 4; ++nq) {
    f4_t al = *(const f4_t*)(alog + (size_t)d * 16 + nq * 4);
#pragma unroll
    for (int j = 0; j < 4; ++j) Av[nq * 4 + j] = -__expf(al[j]);
  }
  f4_t h4[4];
  size_t o = ((size_t)((b * 32 + c) * 2048 + d)) * 16;
#pragma unroll
  for (int nq = 0; nq < 4; ++nq) h4[nq] = *(const f4_t*)(Q + o + nq * 4);
  float Dv = Dw[d];
  int row0 = b * 2048 + c * 64;
  for (int i = 0; i < 64; ++i) {
    size_t row = (size_t)(row0 + i);
    float dlt = b2f(delta_bf[row * 2048 + d]);
    float uv  = b2f(ub[row * 2048 + d]);
    const float* bp = bc + row * 32;
    f4_t Bv[4], Cv[4];
#pragma unroll
    for (int nq = 0; nq < 4; ++nq) { Bv[nq] = *(const f4_t*)(bp + nq * 4); Cv[nq] = *(const f4_t*)(bp + 16 + nq * 4); }
    float du = dlt * uv;
    float y = 0.f;
#pragma unroll
    for (int n = 0; n < 16; ++n) {
      float a = __expf(dlt * Av[n]);
      float hn = a * h4[n >> 2][n & 3] + du * Bv[n >> 2][n & 3];
      h4[n >> 2][n & 3] = hn;
      y += hn * Cv[n >> 2][n & 3];
    }
    float zv = b2f(zy[row * 2048 + d]);
    float ov = (y + Dv * uv) * (zv / (1.f + __expf(-zv)));
    zy[row * 2048 + d] = f2b(ov);
  }
}

// residual + LayerNorm, f32 in/out. One block (256 thr) per row of 1024.
__global__ __launch_bounds__(256)
void ln_kernel(const float* __restrict__ hp, const float* __restrict__ xin,
               const float* __restrict__ lnw, const float* __restrict__ lnb,
               float* __restrict__ outp)
{
  __shared__ float ssum[4], ssq[4];
  int row = blockIdx.x, t = threadIdx.x;
  const float* hr = hp + (size_t)row * 1024;
  const float* xr = xin + (size_t)row * 1024;
  f4_t hv = *(const f4_t*)(hr + t * 4);
  f4_t xv = *(const f4_t*)(xr + t * 4);
  float v[4], s = 0.f, q = 0.f;
#pragma unroll
  for (int j = 0; j < 4; ++j) { v[j] = hv[j] + xv[j]; s += v[j]; q += v[j] * v[j]; }
#pragma unroll
  for (int m = 32; m; m >>= 1) { s += __shfl_xor(s, m, 64); q += __shfl_xor(q, m, 64); }
  int wv = t >> 6;
  if ((t & 63) == 0) { ssum[wv] = s; ssq[wv] = q; }
  __syncthreads();
  s = ssum[0] + ssum[1] + ssum[2] + ssum[3];
  q = ssq[0] + ssq[1] + ssq[2] + ssq[3];
  float mu = s * (1.f / 1024.f);
  float var = q * (1.f / 1024.f) - mu * mu;
  float rs = rsqrtf(var + 1e-5f);
  f4_t o;
#pragma unroll
  for (int j = 0; j < 4; ++j)
    o[j] = (v[j] - mu) * rs * lnw[t * 4 + j] + lnb[t * 4 + j];
  *(f4_t*)(outp + (size_t)row * 1024 + t * 4) = o;
}

extern "C" void kernel_launch(void* const* d_in, const int* in_sizes, int n_in,
                              void* d_out, int out_size, void* d_ws, size_t ws_size,
                              hipStream_t stream)
{
  const float* x      = (const float*)d_in[0];   // [2,2048,1024]
  const float* inW    = (const float*)d_in[1];   // [4096,1024]
  const float* convW  = (const float*)d_in[2];   // [2048,1,4]
  const float* convB  = (const float*)d_in[3];   // [2048]
  const float* xprojW = (const float*)d_in[4];   // [96,2048]
  const float* dtW    = (const float*)d_in[5];   // [2048,64]
  const float* dtB    = (const float*)d_in[6];   // [2048]
  const float* alog   = (const float*)d_in[7];   // [2048,16]
  const float* Dw     = (const float*)d_in[8];   // [2048]
  const float* outW   = (const float*)d_in[9];   // [1024,2048]
  const float* lnw    = (const float*)d_in[10];  // [1024]
  const float* lnb    = (const float*)d_in[11];  // [1024]
  float* out = (float*)d_out;                    // [2,2048,1024] f32 (16 MiB)

  // Workspace (peak 56.23 MB, non-overlapping — round-5 bug was dtWb placed
  // inside xprojWb's 384 KB):
  //  [0,16M):            xi bf16 -> delta bf16 -> hproj f32 [4096,1024]
  //  [16M,32M):          z bf16 -> y bf16 (scan_s3 in place)
  //  [32M,48M):          xb bf16 (8M) + inWb bf16 (8M) -> u bf16 (after gemm0)
  //  [50331648,+512K):   dtA bf16 [4096,64]
  //  [50855936,+512K):   bc f32 [4096,32]
  //  [51380224,+384K):   xprojWb bf16 [96,2048]
  //  [51773440,+256K):   dtWb bf16 [2048,64]
  //  [52035584,+4M):     outWb bf16 [1024,2048]
  // P/Q scratch (8 MB each) live in d_out (dead until ln_kernel).
  char* ws = (char*)d_ws;
  u16*   xiz    = (u16*)(ws);
  u16*   zy     = xiz + 8388608;
  u16*   xb     = (u16*)(ws + 33554432);
  u16*   inWb   = xb + 4194304;
  u16*   u_bf   = (u16*)(ws + 33554432);          // overwrites xb/inWb after gemm0
  u16*   dtA    = (u16*)(ws + 50331648);
  float* bc     = (float*)(ws + 50855936);
  u16*   xprojWb= (u16*)(ws + 51380224);
  u16*   dtWb   = (u16*)(ws + 51773440);
  u16*   outWb  = (u16*)(ws + 52035584);
  u16*   delta  = xiz;                            // overwrites dead xi
  float* hproj  = (float*)(ws);                   // overwrites dead delta
  float* Pbuf   = (float*)d_out;
  float* Qbuf   = (float*)((char*)d_out + 8388608);

  dim3 blk(256);
  // f32 -> bf16 conversions
  cvt_bf16<<<4096, blk, 0, stream>>>(x,      xb,      1048576);
  cvt_bf16<<<4096, blk, 0, stream>>>(inW,    inWb,    1048576);
  cvt_bf16<<<192,  blk, 0, stream>>>(xprojW, xprojWb, 49152);
  cvt_bf16<<<128,  blk, 0, stream>>>(dtW,    dtWb,    32768);
  cvt_bf16<<<2048, blk, 0, stream>>>(outW,   outWb,   524288);

  // in_proj: [4096,1024] x [4096,1024]^T -> xi | z (bf16)
  gemm_bt<0><<<dim3(32, 32), blk, 0, stream>>>(xb, 1024, inWb, 1024, 1024, 4096, xiz, nullptr, nullptr);
  // depthwise causal conv + silu -> u (bf16; overwrites xb/inWb)
  conv_silu<<<32768, blk, 0, stream>>>(xiz, convW, convB, u_bf);
  // x_proj -> dtA bf16 [4096,64] + bc f32 [4096,32]
  gemm_bt<1><<<dim3(1, 32), blk, 0, stream>>>(u_bf, 2048, xprojWb, 2048, 2048, 96, dtA, bc, nullptr);
  // dt_proj + softplus -> delta (bf16, overwrites xi)
  gemm_bt<2><<<dim3(16, 32), blk, 0, stream>>>(dtA, 64, dtWb, 64, 64, 2048, delta, nullptr, dtB);
  // chunk-parallel scan: S1 (P,q) -> combine -> S3 (y, gated, in place over z)
  scan_s1<<<512, blk, 0, stream>>>(delta, u_bf, bc, alog, Pbuf, Qbuf);
  scan_comb<<<256, blk, 0, stream>>>(Pbuf, Qbuf);
  scan_s3<<<512, blk, 0, stream>>>(delta, u_bf, bc, alog, Qbuf, Dw, zy);
  // out_proj: [4096,2048] x [1024,2048]^T -> hproj f32 (overwrites delta region)
  gemm_bt<3><<<dim3(8, 32), blk, 0, stream>>>(zy, 2048, outWb, 2048, 2048, 1024, nullptr, hproj, nullptr);
  // residual + LayerNorm -> f32 out
  ln_kernel<<<4096, blk, 0, stream>>>(hproj, x, lnw, lnb, out);
}

// Round 7
// 364.165 us; speedup vs baseline: 4.8905x; 1.1676x over previous
//
#include <hip/hip_runtime.h>

typedef unsigned short u16;
typedef __attribute__((ext_vector_type(8))) short bf8_t;    // 8 x bf16 (4 VGPRs)
typedef __attribute__((ext_vector_type(4))) float f4_t;     // 4 x f32
typedef __attribute__((ext_vector_type(4))) unsigned short u16x4;

__device__ __forceinline__ float b2f(u16 h) {
  union { unsigned u; float f; } v; v.u = ((unsigned)h) << 16; return v.f;
}
__device__ __forceinline__ u16 f2b(float f) {
  union { float f; unsigned u; } v; v.f = f;
  unsigned u = v.u;
  u += 0x7fffu + ((u >> 16) & 1u);   // round-nearest-even
  return (u16)(u >> 16);
}

#define AS1C(p) ((const __attribute__((address_space(1))) void*)(p))
#define AS3(p)  ((__attribute__((address_space(3))) void*)(p))

// one fused f32 -> bf16 convert over all 5 weight/input arrays
__global__ __launch_bounds__(256)
void cvt_all(const float* __restrict__ x, const float* __restrict__ inW,
             const float* __restrict__ xprojW, const float* __restrict__ dtW,
             const float* __restrict__ outW,
             u16* __restrict__ xb, u16* __restrict__ inWb, u16* __restrict__ xpb,
             u16* __restrict__ dtWb, u16* __restrict__ outWb)
{
  int i = blockIdx.x * 256 + threadIdx.x;      // float4 index, total 2703360
  if (i >= 2703360) return;
  const float* s; u16* d; int off;
  if (i < 1048576)      { s = x;      d = xb;    off = i; }
  else if (i < 2097152) { s = inW;    d = inWb;  off = i - 1048576; }
  else if (i < 2146304) { s = xprojW; d = xpb;   off = i - 2097152; }
  else if (i < 2179072) { s = dtW;    d = dtWb;  off = i - 2146304; }
  else                  { s = outW;   d = outWb; off = i - 2179072; }
  f4_t v = *(const f4_t*)(s + (size_t)off * 4);
  u16x4 o;
#pragma unroll
  for (int j = 0; j < 4; ++j) o[j] = f2b(v[j]);
  *(u16x4*)(d + (size_t)off * 4) = o;
}

// Stage one 128x32 bf16 tile (8 KB) into LDS, XOR-swizzled: granule (r,q)
// holds global colchunk q^((r>>1)&3) — makes fragment ds_read_b128 2-way
// bank-clean (quarter-wave hits all 8 bank-groups). Lane->LDS slot is the
// fixed global_load_lds map (base + lane*16).
__device__ __forceinline__ void stage_wave(const u16* g, int ld, int row0, int rowmax,
                                           int k0, u16* lds, int wid, int lane) {
  int qg = (lane & 3) ^ ((lane >> 3) & 3);    // swizzled colchunk this lane fetches
#pragma unroll
  for (int c = 0; c < 2; ++c) {
    int chunk = wid * 2 + c;
    int r = row0 + chunk * 16 + (lane >> 2);
    if (r > rowmax) r = rowmax;                       // clamp (results discarded later)
    const u16* gp = g + (size_t)r * ld + k0 + qg * 8;
    __builtin_amdgcn_global_load_lds(AS1C(gp), AS3(lds + chunk * 512), 16, 0, 0);
  }
}

// C = A * Bt^T : A[M,K] bf16 row-major (lda), Bt[N,K] bf16 row-major (ldb).
// EPI 0: in_proj  -> o16: n<2048 -> xi[m*2048+n]; else z at o16+8388608
// EPI 1: x_proj   -> split-K partials: of32[(bx*4096+m)*96+n], n<96
// EPI 2: dt_proj  -> o16[m*2048+n] = bf16(softplus(acc + biasf[n]))
// EPI 3: out_proj -> split-K: z=0 -> of32[m*1024+n], z=1 -> of32b[m*1024+n]
template<int EPI>
__global__ __launch_bounds__(256)
void gemm_bt(const u16* __restrict__ A, int lda,
             const u16* __restrict__ Bt, int ldb,
             int Kblk, int Nact,
             u16* __restrict__ o16, float* __restrict__ of32,
             float* __restrict__ of32b, const float* __restrict__ biasf)
{
  __shared__ u16 lsA[128 * 32];
  __shared__ u16 lsB[128 * 32];
  const int tid = threadIdx.x;
  const int wid = tid >> 6, lane = tid & 63;
  const int wm = wid >> 1, wn = wid & 1;          // 2x2 wave grid, 64x64 each
  const int lrow = lane & 15;
  // swizzled k-chunk offset: (kq ^ ((lrow>>1)&3)) * 8  — per-lane constant
  const int lk = (((lane >> 4) ^ ((lane >> 1) & 3)) & 3) * 8;
  const int m0 = blockIdx.y * 128;
  const int n0 = (EPI == 1) ? 0 : blockIdx.x * 128;
  int kbase = 0;
  if (EPI == 1) kbase = blockIdx.x * Kblk;
  if (EPI == 3) kbase = blockIdx.z * Kblk;

  f4_t acc[4][4];
#pragma unroll
  for (int i = 0; i < 4; ++i)
#pragma unroll
    for (int j = 0; j < 4; ++j) acc[i][j] = {0.f, 0.f, 0.f, 0.f};

  for (int kt = kbase; kt < kbase + Kblk; kt += 32) {
    stage_wave(A,  lda, m0, 0x3fffffff, kt, lsA, wid, lane);
    stage_wave(Bt, ldb, n0, Nact - 1,   kt, lsB, wid, lane);
    __syncthreads();
    bf8_t af[4], bfr[4];
#pragma unroll
    for (int mi = 0; mi < 4; ++mi)
      af[mi] = *(const bf8_t*)&lsA[(wm * 64 + mi * 16 + lrow) * 32 + lk];
#pragma unroll
    for (int ni = 0; ni < 4; ++ni)
      bfr[ni] = *(const bf8_t*)&lsB[(wn * 64 + ni * 16 + lrow) * 32 + lk];
#pragma unroll
    for (int mi = 0; mi < 4; ++mi)
#pragma unroll
      for (int ni = 0; ni < 4; ++ni)
        acc[mi][ni] = __builtin_amdgcn_mfma_f32_16x16x32_bf16(af[mi], bfr[ni], acc[mi][ni], 0, 0, 0);
    __syncthreads();
  }

  const int rq = (lane >> 4) * 4;                  // C/D: row=(lane>>4)*4+r, col=lane&15
#pragma unroll
  for (int mi = 0; mi < 4; ++mi) {
#pragma unroll
    for (int ni = 0; ni < 4; ++ni) {
#pragma unroll
      for (int r = 0; r < 4; ++r) {
        int m = m0 + wm * 64 + mi * 16 + rq + r;
        int n = n0 + wn * 64 + ni * 16 + lrow;
        float v = acc[mi][ni][r];
        if (EPI == 0) {
          if (n < 2048) o16[(size_t)m * 2048 + n] = f2b(v);
          else          o16[(size_t)8388608 + (size_t)m * 2048 + (n - 2048)] = f2b(v);
        } else if (EPI == 1) {
          if (n < 96) of32[((size_t)blockIdx.x * 4096 + m) * 96 + n] = v;
        } else if (EPI == 2) {
          float t = v + biasf[n];
          float sp = (t > 20.f) ? t : log1pf(__expf(t));
          o16[(size_t)m * 2048 + n] = f2b(sp);
        } else {
          float* dst = blockIdx.z ? of32b : of32;
          dst[(size_t)m * 1024 + n] = v;
        }
      }
    }
  }
}

// reduce 8 split-K partials of x_proj; emit dtA bf16 [4096,64] + bc f32 [4096,32]
__global__ __launch_bounds__(256)
void xproj_reduce(const float* __restrict__ part, u16* __restrict__ dtA,
                  float* __restrict__ bc)
{
  int idx = blockIdx.x * 256 + threadIdx.x;   // 4096*96
  int m = idx / 96, n = idx - m * 96;
  float s = 0.f;
#pragma unroll
  for (int p = 0; p < 8; ++p) s += part[(size_t)p * 393216 + idx];
  if (n < 64) dtA[(size_t)m * 64 + n] = f2b(s);
  else        bc[(size_t)m * 32 + (n - 64)] = s;
}

// causal depthwise conv1d (window 4) + bias + silu; bf16 in (xi), f32 weights, bf16 out
__global__ __launch_bounds__(256)
void conv_silu(const u16* __restrict__ xib, const float* __restrict__ cw,
               const float* __restrict__ cb, u16* __restrict__ ub)
{
  int idx = blockIdx.x * 256 + threadIdx.x;   // [b*L + l][c], c fastest
  int c = idx & 2047;
  int i = idx >> 11;
  int l = i & 2047;
  float acc = cb[c];
  float w0 = cw[c * 4 + 0], w1 = cw[c * 4 + 1];
  float w2 = cw[c * 4 + 2], w3 = cw[c * 4 + 3];
  const u16* xc = xib + (size_t)i * 2048 + c;
  if (l >= 3) {
    acc += w0 * b2f(xc[-3 * 2048]) + w1 * b2f(xc[-2 * 2048])
         + w2 * b2f(xc[-2048]) + w3 * b2f(xc[0]);
  } else {
    acc += w3 * b2f(xc[0]);
    if (l >= 1) acc += w2 * b2f(xc[-2048]);
    if (l >= 2) acc += w1 * b2f(xc[-2 * 2048]);
  }
  float s = acc / (1.f + __expf(-acc));
  ub[idx] = f2b(s);
}

// ---- chunk-parallel scan, d-in-lane layout. 32 chunks x 64 steps. ----
__global__ __launch_bounds__(256)
void scan_s1(const u16* __restrict__ delta_bf, const u16* __restrict__ ub,
             const float* __restrict__ bc, const float* __restrict__ alog,
             float* __restrict__ P, float* __restrict__ Q)
{
  int blk = blockIdx.x;
  int g = blk & 7, c = (blk >> 3) & 31, b = blk >> 8;
  int d = g * 256 + threadIdx.x;
  float Av[16];
#pragma unroll
  for (int nq = 0; nq < 4; ++nq) {
    f4_t al = *(const f4_t*)(alog + (size_t)d * 16 + nq * 4);
#pragma unroll
    for (int j = 0; j < 4; ++j) Av[nq * 4 + j] = -__expf(al[j]);
  }
  f4_t Pr[4], Qr[4];
#pragma unroll
  for (int nq = 0; nq < 4; ++nq) { Pr[nq] = {1.f,1.f,1.f,1.f}; Qr[nq] = {0.f,0.f,0.f,0.f}; }
  int row0 = b * 2048 + c * 64;
  for (int i = 0; i < 64; ++i) {
    size_t row = (size_t)(row0 + i);
    float dlt = b2f(delta_bf[row * 2048 + d]);
    float uv  = b2f(ub[row * 2048 + d]);
    const float* bp = bc + row * 32;
    f4_t Bv[4];
#pragma unroll
    for (int nq = 0; nq < 4; ++nq) Bv[nq] = *(const f4_t*)(bp + nq * 4);
    float du = dlt * uv;
#pragma unroll
    for (int n = 0; n < 16; ++n) {
      float a = __expf(dlt * Av[n]);
      Qr[n >> 2][n & 3] = a * Qr[n >> 2][n & 3] + du * Bv[n >> 2][n & 3];
      Pr[n >> 2][n & 3] *= a;
    }
  }
  size_t o = ((size_t)((b * 32 + c) * 2048 + d)) * 16;
#pragma unroll
  for (int nq = 0; nq < 4; ++nq) {
    *(f4_t*)(P + o + nq * 4) = Pr[nq];
    *(f4_t*)(Q + o + nq * 4) = Qr[nq];
  }
}

// S2: serial prefix over 32 chunks per (b,d,n); writes incoming-H into Q's slot.
__global__ __launch_bounds__(256)
void scan_comb(const float* __restrict__ P, float* __restrict__ Q)
{
  int idx = blockIdx.x * 256 + threadIdx.x;   // b*32768 + d*16+n
  int b = idx >> 15, dn = idx & 32767;
  size_t base = (size_t)b * 32 * 32768 + dn;
  float H = 0.f;
  for (int c = 0; c < 32; ++c) {
    size_t k = base + (size_t)c * 32768;
    float p = P[k], q = Q[k];
    Q[k] = H;
    H = p * H + q;
  }
}

// S3: re-scan with correct h_in; y = sum_n h*C in regs; fused D-skip + silu(z)
// gate; y overwrites z in place (coalesced bf16 stores).
__global__ __launch_bounds__(256)
void scan_s3(const u16* __restrict__ delta_bf, const u16* __restrict__ ub,
             const float* __restrict__ bc, const float* __restrict__ alog,
             const float* __restrict__ Q, const float* __restrict__ Dw,
             u16* __restrict__ zy)
{
  int blk = blockIdx.x;
  int g = blk & 7, c = (blk >> 3) & 31, b = blk >> 8;
  int d = g * 256 + threadIdx.x;
  float Av[16];
#pragma unroll
  for (int nq = 0; nq < 4; ++nq) {
    f4_t al = *(const f4_t*)(alog + (size_t)d * 16 + nq * 4);
#pragma unroll
    for (int j = 0; j < 4; ++j) Av[nq * 4 + j] = -__expf(al[j]);
  }
  f4_t h4[4];
  size_t o = ((size_t)((b * 32 + c) * 2048 + d)) * 16;
#pragma unroll
  for (int nq = 0; nq < 4; ++nq) h4[nq] = *(const f4_t*)(Q + o + nq * 4);
  float Dv = Dw[d];
  int row0 = b * 2048 + c * 64;
  for (int i = 0; i < 64; ++i) {
    size_t row = (size_t)(row0 + i);
    float dlt = b2f(delta_bf[row * 2048 + d]);
    float uv  = b2f(ub[row * 2048 + d]);
    const float* bp = bc + row * 32;
    f4_t Bv[4], Cv[4];
#pragma unroll
    for (int nq = 0; nq < 4; ++nq) { Bv[nq] = *(const f4_t*)(bp + nq * 4); Cv[nq] = *(const f4_t*)(bp + 16 + nq * 4); }
    float du = dlt * uv;
    float y = 0.f;
#pragma unroll
    for (int n = 0; n < 16; ++n) {
      float a = __expf(dlt * Av[n]);
      float hn = a * h4[n >> 2][n & 3] + du * Bv[n >> 2][n & 3];
      h4[n >> 2][n & 3] = hn;
      y += hn * Cv[n >> 2][n & 3];
    }
    float zv = b2f(zy[row * 2048 + d]);
    float ov = (y + Dv * uv) * (zv / (1.f + __expf(-zv)));
    zy[row * 2048 + d] = f2b(ov);
  }
}

// residual + LayerNorm over two out_proj partials, f32 in/out.
__global__ __launch_bounds__(256)
void ln_kernel(const float* __restrict__ hp0, const float* __restrict__ hp1,
               const float* __restrict__ xin,
               const float* __restrict__ lnw, const float* __restrict__ lnb,
               float* __restrict__ outp)
{
  __shared__ float ssum[4], ssq[4];
  int row = blockIdx.x, t = threadIdx.x;
  f4_t h0 = *(const f4_t*)(hp0 + (size_t)row * 1024 + t * 4);
  f4_t h1 = *(const f4_t*)(hp1 + (size_t)row * 1024 + t * 4);
  f4_t xv = *(const f4_t*)(xin + (size_t)row * 1024 + t * 4);
  float v[4], s = 0.f, q = 0.f;
#pragma unroll
  for (int j = 0; j < 4; ++j) { v[j] = h0[j] + h1[j] + xv[j]; s += v[j]; q += v[j] * v[j]; }
#pragma unroll
  for (int m = 32; m; m >>= 1) { s += __shfl_xor(s, m, 64); q += __shfl_xor(q, m, 64); }
  int wv = t >> 6;
  if ((t & 63) == 0) { ssum[wv] = s; ssq[wv] = q; }
  __syncthreads();
  s = ssum[0] + ssum[1] + ssum[2] + ssum[3];
  q = ssq[0] + ssq[1] + ssq[2] + ssq[3];
  float mu = s * (1.f / 1024.f);
  float var = q * (1.f / 1024.f) - mu * mu;
  float rs = rsqrtf(var + 1e-5f);
  f4_t o;
#pragma unroll
  for (int j = 0; j < 4; ++j)
    o[j] = (v[j] - mu) * rs * lnw[t * 4 + j] + lnb[t * 4 + j];
  *(f4_t*)(outp + (size_t)row * 1024 + t * 4) = o;
}

extern "C" void kernel_launch(void* const* d_in, const int* in_sizes, int n_in,
                              void* d_out, int out_size, void* d_ws, size_t ws_size,
                              hipStream_t stream)
{
  const float* x      = (const float*)d_in[0];   // [2,2048,1024]
  const float* inW    = (const float*)d_in[1];   // [4096,1024]
  const float* convW  = (const float*)d_in[2];   // [2048,1,4]
  const float* convB  = (const float*)d_in[3];   // [2048]
  const float* xprojW = (const float*)d_in[4];   // [96,2048]
  const float* dtW    = (const float*)d_in[5];   // [2048,64]
  const float* dtB    = (const float*)d_in[6];   // [2048]
  const float* alog   = (const float*)d_in[7];   // [2048,16]
  const float* Dw     = (const float*)d_in[8];   // [2048]
  const float* outW   = (const float*)d_in[9];   // [1024,2048]
  const float* lnw    = (const float*)d_in[10];  // [1024]
  const float* lnb    = (const float*)d_in[11];  // [1024]
  float* out = (float*)d_out;                    // [2,2048,1024] f32 (16 MiB)

  // Workspace (peak 56.23 MB, layout proven in round 6):
  //  [0,16M):            xi bf16 -> delta bf16 -> out_proj partial1 f32
  //  [16M,32M):          z bf16 -> y bf16 (scan_s3 in place)
  //  [32M,48M):          xb bf16 (8M) + inWb bf16 (8M) -> u bf16 (after gemm0)
  //  [50331648,+512K):   dtA bf16 [4096,64]
  //  [50855936,+512K):   bc f32 [4096,32]
  //  [51380224,+384K):   xprojWb bf16 [96,2048]
  //  [51773440,+256K):   dtWb bf16 [2048,64]
  //  [52035584,+4M):     outWb bf16 [1024,2048]
  // d_out doubles as scratch: x_proj split-K partials (12.6 MB) -> P/Q (16 MB)
  // -> out_proj partial0 (16 MB) -> final output (ln reads then writes in place).
  char* ws = (char*)d_ws;
  u16*   xiz    = (u16*)(ws);
  u16*   zy     = xiz + 8388608;
  u16*   xb     = (u16*)(ws + 33554432);
  u16*   inWb   = xb + 4194304;
  u16*   u_bf   = (u16*)(ws + 33554432);          // overwrites xb/inWb after gemm0
  u16*   dtA    = (u16*)(ws + 50331648);
  float* bc     = (float*)(ws + 50855936);
  u16*   xprojWb= (u16*)(ws + 51380224);
  u16*   dtWb   = (u16*)(ws + 51773440);
  u16*   outWb  = (u16*)(ws + 52035584);
  u16*   delta  = xiz;                            // overwrites dead xi
  float* hpart1 = (float*)(ws);                   // out_proj partial1 (delta dead)
  float* hpart0 = (float*)d_out;                  // out_proj partial0
  float* xpart  = (float*)d_out;                  // x_proj partials [8][4096][96]
  float* Pbuf   = (float*)d_out;
  float* Qbuf   = (float*)((char*)d_out + 8388608);

  dim3 blk(256);
  // fused f32 -> bf16 conversions (one launch)
  cvt_all<<<10560, blk, 0, stream>>>(x, inW, xprojW, dtW, outW,
                                     xb, inWb, xprojWb, dtWb, outWb);
  // in_proj: [4096,1024] x [4096,1024]^T -> xi | z (bf16)
  gemm_bt<0><<<dim3(32, 32), blk, 0, stream>>>(xb, 1024, inWb, 1024, 1024, 4096, xiz, nullptr, nullptr, nullptr);
  // depthwise causal conv + silu -> u (bf16; overwrites xb/inWb)
  conv_silu<<<32768, blk, 0, stream>>>(xiz, convW, convB, u_bf);
  // x_proj split-K (8 x 256): partials into d_out
  gemm_bt<1><<<dim3(8, 32), blk, 0, stream>>>(u_bf, 2048, xprojWb, 2048, 256, 96, nullptr, xpart, nullptr, nullptr);
  xproj_reduce<<<1536, blk, 0, stream>>>(xpart, dtA, bc);
  // dt_proj + softplus -> delta (bf16, overwrites xi)
  gemm_bt<2><<<dim3(16, 32), blk, 0, stream>>>(dtA, 64, dtWb, 64, 64, 2048, delta, nullptr, nullptr, dtB);
  // chunk-parallel scan: S1 (P,q) -> combine -> S3 (y, gated, in place over z)
  scan_s1<<<512, blk, 0, stream>>>(delta, u_bf, bc, alog, Pbuf, Qbuf);
  scan_comb<<<256, blk, 0, stream>>>(Pbuf, Qbuf);
  scan_s3<<<512, blk, 0, stream>>>(delta, u_bf, bc, alog, Qbuf, Dw, zy);
  // out_proj split-K (2 x 1024): partial0 -> d_out, partial1 -> ws[0,16M)
  gemm_bt<3><<<dim3(8, 32, 2), blk, 0, stream>>>(zy, 2048, outWb, 2048, 1024, 1024, nullptr, hpart0, hpart1, nullptr);
  // residual + LayerNorm (sums both partials) -> f32 out (in place over partial0)
  ln_kernel<<<4096, blk, 0, stream>>>(hpart0, hpart1, x, lnw, lnb, out);
}

// Round 8
// 362.503 us; speedup vs baseline: 4.9129x; 1.0046x over previous
//
#include <hip/hip_runtime.h>

typedef unsigned short u16;
typedef __attribute__((ext_vector_type(8))) short bf8_t;    // 8 x bf16 (4 VGPRs)
typedef __attribute__((ext_vector_type(4))) float f4_t;     // 4 x f32
typedef __attribute__((ext_vector_type(4))) unsigned short u16x4;
typedef __attribute__((ext_vector_type(8))) unsigned short u16x8;

__device__ __forceinline__ float b2f(u16 h) {
  union { unsigned u; float f; } v; v.u = ((unsigned)h) << 16; return v.f;
}
__device__ __forceinline__ u16 f2b(float f) {
  union { float f; unsigned u; } v; v.f = f;
  unsigned u = v.u;
  u += 0x7fffu + ((u >> 16) & 1u);   // round-nearest-even
  return (u16)(u >> 16);
}

#define AS1C(p) ((const __attribute__((address_space(1))) void*)(p))
#define AS3(p)  ((__attribute__((address_space(3))) void*)(p))

// one fused f32 -> bf16 convert over all 5 weight/input arrays
__global__ __launch_bounds__(256)
void cvt_all(const float* __restrict__ x, const float* __restrict__ inW,
             const float* __restrict__ xprojW, const float* __restrict__ dtW,
             const float* __restrict__ outW,
             u16* __restrict__ xb, u16* __restrict__ inWb, u16* __restrict__ xpb,
             u16* __restrict__ dtWb, u16* __restrict__ outWb)
{
  int i = blockIdx.x * 256 + threadIdx.x;      // float4 index, total 2703360
  if (i >= 2703360) return;
  const float* s; u16* d; int off;
  if (i < 1048576)      { s = x;      d = xb;    off = i; }
  else if (i < 2097152) { s = inW;    d = inWb;  off = i - 1048576; }
  else if (i < 2146304) { s = xprojW; d = xpb;   off = i - 2097152; }
  else if (i < 2179072) { s = dtW;    d = dtWb;  off = i - 2146304; }
  else                  { s = outW;   d = outWb; off = i - 2179072; }
  f4_t v = *(const f4_t*)(s + (size_t)off * 4);
  u16x4 o;
#pragma unroll
  for (int j = 0; j < 4; ++j) o[j] = f2b(v[j]);
  *(u16x4*)(d + (size_t)off * 4) = o;
}

// Stage one 128x32 bf16 tile (8 KB) into LDS, XOR-swizzled: granule (r,q)
// holds global colchunk q^((r>>1)&3) — bank-conflict-free fragment reads.
__device__ __forceinline__ void stage_wave(const u16* g, int ld, int row0, int rowmax,
                                           int k0, u16* lds, int wid, int lane) {
  int qg = (lane & 3) ^ ((lane >> 3) & 3);    // swizzled colchunk this lane fetches
#pragma unroll
  for (int c = 0; c < 2; ++c) {
    int chunk = wid * 2 + c;
    int r = row0 + chunk * 16 + (lane >> 2);
    if (r > rowmax) r = rowmax;                       // clamp (results discarded later)
    const u16* gp = g + (size_t)r * ld + k0 + qg * 8;
    __builtin_amdgcn_global_load_lds(AS1C(gp), AS3(lds + chunk * 512), 16, 0, 0);
  }
}

// C = A * Bt^T : A[M,K] bf16 row-major (lda), Bt[N,K] bf16 row-major (ldb).
// EPI 0: in_proj  -> o16: n<2048 -> xi[m*2048+n]; else z at o16+8388608
// EPI 1: x_proj   -> split-K partials: of32[(bx*4096+m)*96+n], n<96
// EPI 2: dt_proj  -> o16[m*2048+n] = bf16(softplus(acc + biasf[n]))
// EPI 3: out_proj -> split-K: z=0 -> of32[m*1024+n], z=1 -> of32b[m*1024+n]
template<int EPI>
__device__ __forceinline__ void gemm_body(const u16* __restrict__ A, int lda,
             const u16* __restrict__ Bt, int ldb,
             int Kblk, int Nact,
             u16* __restrict__ o16, float* __restrict__ of32,
             float* __restrict__ of32b, const float* __restrict__ biasf)
{
  __shared__ u16 lsA[128 * 32];
  __shared__ u16 lsB[128 * 32];
  const int tid = threadIdx.x;
  const int wid = tid >> 6, lane = tid & 63;
  const int wm = wid >> 1, wn = wid & 1;          // 2x2 wave grid, 64x64 each
  const int lrow = lane & 15;
  // swizzled k-chunk offset: (kq ^ ((lrow>>1)&3)) * 8  — per-lane constant
  const int lk = (((lane >> 4) ^ ((lane >> 1) & 3)) & 3) * 8;
  const int m0 = blockIdx.y * 128;
  const int n0 = (EPI == 1) ? 0 : blockIdx.x * 128;
  int kbase = 0;
  if (EPI == 1) kbase = blockIdx.x * Kblk;
  if (EPI == 3) kbase = blockIdx.z * Kblk;

  f4_t acc[4][4];
#pragma unroll
  for (int i = 0; i < 4; ++i)
#pragma unroll
    for (int j = 0; j < 4; ++j) acc[i][j] = {0.f, 0.f, 0.f, 0.f};

  for (int kt = kbase; kt < kbase + Kblk; kt += 32) {
    stage_wave(A,  lda, m0, 0x3fffffff, kt, lsA, wid, lane);
    stage_wave(Bt, ldb, n0, Nact - 1,   kt, lsB, wid, lane);
    __syncthreads();
    bf8_t af[4], bfr[4];
#pragma unroll
    for (int mi = 0; mi < 4; ++mi)
      af[mi] = *(const bf8_t*)&lsA[(wm * 64 + mi * 16 + lrow) * 32 + lk];
#pragma unroll
    for (int ni = 0; ni < 4; ++ni)
      bfr[ni] = *(const bf8_t*)&lsB[(wn * 64 + ni * 16 + lrow) * 32 + lk];
#pragma unroll
    for (int mi = 0; mi < 4; ++mi)
#pragma unroll
      for (int ni = 0; ni < 4; ++ni)
        acc[mi][ni] = __builtin_amdgcn_mfma_f32_16x16x32_bf16(af[mi], bfr[ni], acc[mi][ni], 0, 0, 0);
    __syncthreads();
  }

  const int rq = (lane >> 4) * 4;                  // C/D: row=(lane>>4)*4+r, col=lane&15
#pragma unroll
  for (int mi = 0; mi < 4; ++mi) {
#pragma unroll
    for (int ni = 0; ni < 4; ++ni) {
#pragma unroll
      for (int r = 0; r < 4; ++r) {
        int m = m0 + wm * 64 + mi * 16 + rq + r;
        int n = n0 + wn * 64 + ni * 16 + lrow;
        float v = acc[mi][ni][r];
        if (EPI == 0) {
          if (n < 2048) o16[(size_t)m * 2048 + n] = f2b(v);
          else          o16[(size_t)8388608 + (size_t)m * 2048 + (n - 2048)] = f2b(v);
        } else if (EPI == 1) {
          if (n < 96) of32[((size_t)blockIdx.x * 4096 + m) * 96 + n] = v;
        } else if (EPI == 2) {
          float t = v + biasf[n];
          float sp = (t > 20.f) ? t : log1pf(__expf(t));
          o16[(size_t)m * 2048 + n] = f2b(sp);
        } else {
          float* dst = blockIdx.z ? of32b : of32;
          dst[(size_t)m * 1024 + n] = v;
        }
      }
    }
  }
}

// distinct names per GEMM so rocprof ranks them individually
__global__ __launch_bounds__(256)
void gemm_in(const u16* A, int lda, const u16* Bt, int ldb, int Kblk, int Nact,
             u16* o16, float* of32, float* of32b, const float* biasf)
{ gemm_body<0>(A, lda, Bt, ldb, Kblk, Nact, o16, of32, of32b, biasf); }

__global__ __launch_bounds__(256)
void gemm_xp(const u16* A, int lda, const u16* Bt, int ldb, int Kblk, int Nact,
             u16* o16, float* of32, float* of32b, const float* biasf)
{ gemm_body<1>(A, lda, Bt, ldb, Kblk, Nact, o16, of32, of32b, biasf); }

__global__ __launch_bounds__(256)
void gemm_dt(const u16* A, int lda, const u16* Bt, int ldb, int Kblk, int Nact,
             u16* o16, float* of32, float* of32b, const float* biasf)
{ gemm_body<2>(A, lda, Bt, ldb, Kblk, Nact, o16, of32, of32b, biasf); }

__global__ __launch_bounds__(256)
void gemm_out(const u16* A, int lda, const u16* Bt, int ldb, int Kblk, int Nact,
              u16* o16, float* of32, float* of32b, const float* biasf)
{ gemm_body<3>(A, lda, Bt, ldb, Kblk, Nact, o16, of32, of32b, biasf); }

// reduce 8 split-K partials of x_proj; emit dtA bf16 [4096,64] + bc f32 [4096,32]
__global__ __launch_bounds__(256)
void xproj_reduce(const float* __restrict__ part, u16* __restrict__ dtA,
                  float* __restrict__ bc)
{
  int idx = blockIdx.x * 256 + threadIdx.x;   // 4096*96
  int m = idx / 96, n = idx - m * 96;
  float s = 0.f;
#pragma unroll
  for (int p = 0; p < 8; ++p) s += part[(size_t)p * 393216 + idx];
  if (n < 64) dtA[(size_t)m * 64 + n] = f2b(s);
  else        bc[(size_t)m * 32 + (n - 64)] = s;
}

// causal depthwise conv1d (window 4) + bias + silu; vectorized 8 channels/thread
__global__ __launch_bounds__(256)
void conv_silu(const u16* __restrict__ xib, const float* __restrict__ cw,
               const float* __restrict__ cb, u16* __restrict__ ub)
{
  int i = blockIdx.x * 256 + threadIdx.x;     // 1,048,576 threads
  int c8 = (i & 255) * 8;
  int row = i >> 8;                           // b*2048 + l
  int l = row & 2047;
  const u16* base = xib + (size_t)row * 2048 + c8;
  u16x8 x0 = {0,0,0,0,0,0,0,0}, x1 = x0, x2 = x0, x3;
  x3 = *(const u16x8*)(base);
  if (l >= 1) x2 = *(const u16x8*)(base - 2048);
  if (l >= 2) x1 = *(const u16x8*)(base - 2 * 2048);
  if (l >= 3) x0 = *(const u16x8*)(base - 3 * 2048);
  f4_t cb0 = *(const f4_t*)(cb + c8);
  f4_t cb1 = *(const f4_t*)(cb + c8 + 4);
  u16x8 o;
#pragma unroll
  for (int j = 0; j < 8; ++j) {
    f4_t w = *(const f4_t*)(cw + (size_t)(c8 + j) * 4);
    float a = (j < 4 ? cb0[j] : cb1[j - 4])
            + w[0] * b2f(x0[j]) + w[1] * b2f(x1[j])
            + w[2] * b2f(x2[j]) + w[3] * b2f(x3[j]);
    float s = a / (1.f + __expf(-a));
    o[j] = f2b(s);
  }
  *(u16x8*)(ub + (size_t)row * 2048 + c8) = o;
}

// ---- chunk-parallel scan, d-in-lane layout. 32 chunks x 64 steps. ----
__global__ __launch_bounds__(256)
void scan_s1(const u16* __restrict__ delta_bf, const u16* __restrict__ ub,
             const float* __restrict__ bc, const float* __restrict__ alog,
             float* __restrict__ P, float* __restrict__ Q)
{
  int blk = blockIdx.x;
  int g = blk & 7, c = (blk >> 3) & 31, b = blk >> 8;
  int d = g * 256 + threadIdx.x;
  float Av[16];
#pragma unroll
  for (int nq = 0; nq < 4; ++nq) {
    f4_t al = *(const f4_t*)(alog + (size_t)d * 16 + nq * 4);
#pragma unroll
    for (int j = 0; j < 4; ++j) Av[nq * 4 + j] = -__expf(al[j]);
  }
  f4_t Pr[4], Qr[4];
#pragma unroll
  for (int nq = 0; nq < 4; ++nq) { Pr[nq] = {1.f,1.f,1.f,1.f}; Qr[nq] = {0.f,0.f,0.f,0.f}; }
  int row0 = b * 2048 + c * 64;
  for (int i = 0; i < 64; ++i) {
    size_t row = (size_t)(row0 + i);
    float dlt = b2f(delta_bf[row * 2048 + d]);
    float uv  = b2f(ub[row * 2048 + d]);
    const float* bp = bc + row * 32;
    f4_t Bv[4];
#pragma unroll
    for (int nq = 0; nq < 4; ++nq) Bv[nq] = *(const f4_t*)(bp + nq * 4);
    float du = dlt * uv;
#pragma unroll
    for (int n = 0; n < 16; ++n) {
      float a = __expf(dlt * Av[n]);
      Qr[n >> 2][n & 3] = a * Qr[n >> 2][n & 3] + du * Bv[n >> 2][n & 3];
      Pr[n >> 2][n & 3] *= a;
    }
  }
  size_t o = ((size_t)((b * 32 + c) * 2048 + d)) * 16;
#pragma unroll
  for (int nq = 0; nq < 4; ++nq) {
    *(f4_t*)(P + o + nq * 4) = Pr[nq];
    *(f4_t*)(Q + o + nq * 4) = Qr[nq];
  }
}

// S2: serial prefix over 32 chunks per (b,d,n); writes incoming-H into Q's slot.
__global__ __launch_bounds__(256)
void scan_comb(const float* __restrict__ P, float* __restrict__ Q)
{
  int idx = blockIdx.x * 256 + threadIdx.x;   // b*32768 + d*16+n
  int b = idx >> 15, dn = idx & 32767;
  size_t base = (size_t)b * 32 * 32768 + dn;
  float H = 0.f;
  for (int c = 0; c < 32; ++c) {
    size_t k = base + (size_t)c * 32768;
    float p = P[k], q = Q[k];
    Q[k] = H;
    H = p * H + q;
  }
}

// S3: re-scan with correct h_in; y = sum_n h*C in regs; fused D-skip + silu(z)
// gate; y overwrites z in place (coalesced bf16 stores).
__global__ __launch_bounds__(256)
void scan_s3(const u16* __restrict__ delta_bf, const u16* __restrict__ ub,
             const float* __restrict__ bc, const float* __restrict__ alog,
             const float* __restrict__ Q, const float* __restrict__ Dw,
             u16* __restrict__ zy)
{
  int blk = blockIdx.x;
  int g = blk & 7, c = (blk >> 3) & 31, b = blk >> 8;
  int d = g * 256 + threadIdx.x;
  float Av[16];
#pragma unroll
  for (int nq = 0; nq < 4; ++nq) {
    f4_t al = *(const f4_t*)(alog + (size_t)d * 16 + nq * 4);
#pragma unroll
    for (int j = 0; j < 4; ++j) Av[nq * 4 + j] = -__expf(al[j]);
  }
  f4_t h4[4];
  size_t o = ((size_t)((b * 32 + c) * 2048 + d)) * 16;
#pragma unroll
  for (int nq = 0; nq < 4; ++nq) h4[nq] = *(const f4_t*)(Q + o + nq * 4);
  float Dv = Dw[d];
  int row0 = b * 2048 + c * 64;
  for (int i = 0; i < 64; ++i) {
    size_t row = (size_t)(row0 + i);
    float dlt = b2f(delta_bf[row * 2048 + d]);
    float uv  = b2f(ub[row * 2048 + d]);
    const float* bp = bc + row * 32;
    f4_t Bv[4], Cv[4];
#pragma unroll
    for (int nq = 0; nq < 4; ++nq) { Bv[nq] = *(const f4_t*)(bp + nq * 4); Cv[nq] = *(const f4_t*)(bp + 16 + nq * 4); }
    float du = dlt * uv;
    float y = 0.f;
#pragma unroll
    for (int n = 0; n < 16; ++n) {
      float a = __expf(dlt * Av[n]);
      float hn = a * h4[n >> 2][n & 3] + du * Bv[n >> 2][n & 3];
      h4[n >> 2][n & 3] = hn;
      y += hn * Cv[n >> 2][n & 3];
    }
    float zv = b2f(zy[row * 2048 + d]);
    float ov = (y + Dv * uv) * (zv / (1.f + __expf(-zv)));
    zy[row * 2048 + d] = f2b(ov);
  }
}

// residual + LayerNorm over two out_proj partials, f32 in/out.
__global__ __launch_bounds__(256)
void ln_kernel(const float* __restrict__ hp0, const float* __restrict__ hp1,
               const float* __restrict__ xin,
               const float* __restrict__ lnw, const float* __restrict__ lnb,
               float* __restrict__ outp)
{
  __shared__ float ssum[4], ssq[4];
  int row = blockIdx.x, t = threadIdx.x;
  f4_t h0 = *(const f4_t*)(hp0 + (size_t)row * 1024 + t * 4);
  f4_t h1 = *(const f4_t*)(hp1 + (size_t)row * 1024 + t * 4);
  f4_t xv = *(const f4_t*)(xin + (size_t)row * 1024 + t * 4);
  float v[4], s = 0.f, q = 0.f;
#pragma unroll
  for (int j = 0; j < 4; ++j) { v[j] = h0[j] + h1[j] + xv[j]; s += v[j]; q += v[j] * v[j]; }
#pragma unroll
  for (int m = 32; m; m >>= 1) { s += __shfl_xor(s, m, 64); q += __shfl_xor(q, m, 64); }
  int wv = t >> 6;
  if ((t & 63) == 0) { ssum[wv] = s; ssq[wv] = q; }
  __syncthreads();
  s = ssum[0] + ssum[1] + ssum[2] + ssum[3];
  q = ssq[0] + ssq[1] + ssq[2] + ssq[3];
  float mu = s * (1.f / 1024.f);
  float var = q * (1.f / 1024.f) - mu * mu;
  float rs = rsqrtf(var + 1e-5f);
  f4_t o;
#pragma unroll
  for (int j = 0; j < 4; ++j)
    o[j] = (v[j] - mu) * rs * lnw[t * 4 + j] + lnb[t * 4 + j];
  *(f4_t*)(outp + (size_t)row * 1024 + t * 4) = o;
}

extern "C" void kernel_launch(void* const* d_in, const int* in_sizes, int n_in,
                              void* d_out, int out_size, void* d_ws, size_t ws_size,
                              hipStream_t stream)
{
  const float* x      = (const float*)d_in[0];   // [2,2048,1024]
  const float* inW    = (const float*)d_in[1];   // [4096,1024]
  const float* convW  = (const float*)d_in[2];   // [2048,1,4]
  const float* convB  = (const float*)d_in[3];   // [2048]
  const float* xprojW = (const float*)d_in[4];   // [96,2048]
  const float* dtW    = (const float*)d_in[5];   // [2048,64]
  const float* dtB    = (const float*)d_in[6];   // [2048]
  const float* alog   = (const float*)d_in[7];   // [2048,16]
  const float* Dw     = (const float*)d_in[8];   // [2048]
  const float* outW   = (const float*)d_in[9];   // [1024,2048]
  const float* lnw    = (const float*)d_in[10];  // [1024]
  const float* lnb    = (const float*)d_in[11];  // [1024]
  float* out = (float*)d_out;                    // [2,2048,1024] f32 (16 MiB)

  // Workspace (peak 56.23 MB, layout proven in rounds 6-7):
  //  [0,16M):            xi bf16 -> delta bf16 -> out_proj partial1 f32
  //  [16M,32M):          z bf16 -> y bf16 (scan_s3 in place)
  //  [32M,48M):          xb bf16 (8M) + inWb bf16 (8M) -> u bf16 (after gemm_in)
  //  [50331648,+512K):   dtA bf16 [4096,64]
  //  [50855936,+512K):   bc f32 [4096,32]
  //  [51380224,+384K):   xprojWb bf16 [96,2048]
  //  [51773440,+256K):   dtWb bf16 [2048,64]
  //  [52035584,+4M):     outWb bf16 [1024,2048]
  // d_out doubles as scratch: x_proj split-K partials (12.6 MB) -> P/Q (16 MB)
  // -> out_proj partial0 (16 MB) -> final output (ln reads then writes in place).
  char* ws = (char*)d_ws;
  u16*   xiz    = (u16*)(ws);
  u16*   zy     = xiz + 8388608;
  u16*   xb     = (u16*)(ws + 33554432);
  u16*   inWb   = xb + 4194304;
  u16*   u_bf   = (u16*)(ws + 33554432);          // overwrites xb/inWb after gemm_in
  u16*   dtA    = (u16*)(ws + 50331648);
  float* bc     = (float*)(ws + 50855936);
  u16*   xprojWb= (u16*)(ws + 51380224);
  u16*   dtWb   = (u16*)(ws + 51773440);
  u16*   outWb  = (u16*)(ws + 52035584);
  u16*   delta  = xiz;                            // overwrites dead xi
  float* hpart1 = (float*)(ws);                   // out_proj partial1 (delta dead)
  float* hpart0 = (float*)d_out;                  // out_proj partial0
  float* xpart  = (float*)d_out;                  // x_proj partials [8][4096][96]
  float* Pbuf   = (float*)d_out;
  float* Qbuf   = (float*)((char*)d_out + 8388608);

  dim3 blk(256);
  // fused f32 -> bf16 conversions (one launch)
  cvt_all<<<10560, blk, 0, stream>>>(x, inW, xprojW, dtW, outW,
                                     xb, inWb, xprojWb, dtWb, outWb);
  // in_proj: [4096,1024] x [4096,1024]^T -> xi | z (bf16)
  gemm_in<<<dim3(32, 32), blk, 0, stream>>>(xb, 1024, inWb, 1024, 1024, 4096, xiz, nullptr, nullptr, nullptr);
  // depthwise causal conv + silu -> u (bf16; overwrites xb/inWb)
  conv_silu<<<4096, blk, 0, stream>>>(xiz, convW, convB, u_bf);
  // x_proj split-K (8 x 256): partials into d_out
  gemm_xp<<<dim3(8, 32), blk, 0, stream>>>(u_bf, 2048, xprojWb, 2048, 256, 96, nullptr, xpart, nullptr, nullptr);
  xproj_reduce<<<1536, blk, 0, stream>>>(xpart, dtA, bc);
  // dt_proj + softplus -> delta (bf16, overwrites xi)
  gemm_dt<<<dim3(16, 32), blk, 0, stream>>>(dtA, 64, dtWb, 64, 64, 2048, delta, nullptr, nullptr, dtB);
  // chunk-parallel scan: S1 (P,q) -> combine -> S3 (y, gated, in place over z)
  scan_s1<<<512, blk, 0, stream>>>(delta, u_bf, bc, alog, Pbuf, Qbuf);
  scan_comb<<<256, blk, 0, stream>>>(Pbuf, Qbuf);
  scan_s3<<<512, blk, 0, stream>>>(delta, u_bf, bc, alog, Qbuf, Dw, zy);
  // out_proj split-K (2 x 1024): partial0 -> d_out, partial1 -> ws[0,16M)
  gemm_out<<<dim3(8, 32, 2), blk, 0, stream>>>(zy, 2048, outWb, 2048, 1024, 1024, nullptr, hpart0, hpart1, nullptr);
  // residual + LayerNorm (sums both partials) -> f32 out (in place over partial0)
  ln_kernel<<<4096, blk, 0, stream>>>(hpart0, hpart1, x, lnw, lnb, out);
}

// Round 9
// 339.252 us; speedup vs baseline: 5.2496x; 1.0685x over previous
//
#include <hip/hip_runtime.h>

typedef unsigned short u16;
typedef __attribute__((ext_vector_type(8))) short bf8_t;    // 8 x bf16 (4 VGPRs)
typedef __attribute__((ext_vector_type(4))) float f4_t;     // 4 x f32
typedef __attribute__((ext_vector_type(4))) unsigned short u16x4;
typedef __attribute__((ext_vector_type(8))) unsigned short u16x8;

__device__ __forceinline__ float b2f(u16 h) {
  union { unsigned u; float f; } v; v.u = ((unsigned)h) << 16; return v.f;
}
__device__ __forceinline__ u16 f2b(float f) {
  union { float f; unsigned u; } v; v.f = f;
  unsigned u = v.u;
  u += 0x7fffu + ((u >> 16) & 1u);   // round-nearest-even
  return (u16)(u >> 16);
}

#define AS1C(p) ((const __attribute__((address_space(1))) void*)(p))
#define AS3(p)  ((__attribute__((address_space(3))) void*)(p))

// one fused f32 -> bf16 convert over all 5 weight/input arrays
__global__ __launch_bounds__(256)
void cvt_all(const float* __restrict__ x, const float* __restrict__ inW,
             const float* __restrict__ xprojW, const float* __restrict__ dtW,
             const float* __restrict__ outW,
             u16* __restrict__ xb, u16* __restrict__ inWb, u16* __restrict__ xpb,
             u16* __restrict__ dtWb, u16* __restrict__ outWb)
{
  int i = blockIdx.x * 256 + threadIdx.x;      // float4 index, total 2703360
  if (i >= 2703360) return;
  const float* s; u16* d; int off;
  if (i < 1048576)      { s = x;      d = xb;    off = i; }
  else if (i < 2097152) { s = inW;    d = inWb;  off = i - 1048576; }
  else if (i < 2146304) { s = xprojW; d = xpb;   off = i - 2097152; }
  else if (i < 2179072) { s = dtW;    d = dtWb;  off = i - 2146304; }
  else                  { s = outW;   d = outWb; off = i - 2179072; }
  f4_t v = *(const f4_t*)(s + (size_t)off * 4);
  u16x4 o;
#pragma unroll
  for (int j = 0; j < 4; ++j) o[j] = f2b(v[j]);
  *(u16x4*)(d + (size_t)off * 4) = o;
}

// Stage one 128x64 bf16 tile (16 KB) into LDS, XOR-swizzled: granule (r,q)
// holds global colchunk q^(r&7). Staging lane i (chunk of 8 rows) fetches
// colchunk (i&7)^((i>>3)&7); reader uses granule (g ^ (row&7)). Bank-quad
// depends only on q_l -> 8 lanes per 4-bank group = 2/bank = conflict-free.
__device__ __forceinline__ void stage64(const u16* g, int ld, int row0, int rowmax,
                                        int k0, u16* lds, int wid, int lane) {
  int qg = (lane & 7) ^ ((lane >> 3) & 7);
#pragma unroll
  for (int c = 0; c < 4; ++c) {
    int chunk = wid * 4 + c;
    int r = row0 + chunk * 8 + (lane >> 3);
    if (r > rowmax) r = rowmax;                       // clamp (results discarded later)
    const u16* gp = g + (size_t)r * ld + k0 + qg * 8;
    __builtin_amdgcn_global_load_lds(AS1C(gp), AS3(lds + chunk * 512), 16, 0, 0);
  }
}

// C = A * Bt^T : A[M,K] bf16 row-major (lda), Bt[N,K] bf16 row-major (ldb).
// BK=64 (two 32-k half-steps per barrier epoch).
// EPI 0: in_proj  -> o16: n<2048 -> xi[m*2048+n]; else z at o16+8388608
// EPI 1: x_proj   -> split-K partials: of32[(bx*4096+m)*96+n], n<96
// EPI 2: dt_proj  -> o16[m*2048+n] = bf16(softplus(acc + biasf[n]))
// EPI 3: out_proj -> split-K: z=0 -> of32[m*1024+n], z=1 -> of32b[m*1024+n]
template<int EPI>
__device__ __forceinline__ void gemm_body(const u16* __restrict__ A, int lda,
             const u16* __restrict__ Bt, int ldb,
             int Kblk, int Nact,
             u16* __restrict__ o16, float* __restrict__ of32,
             float* __restrict__ of32b, const float* __restrict__ biasf)
{
  __shared__ u16 lsA[128 * 64];
  __shared__ u16 lsB[128 * 64];
  const int tid = threadIdx.x;
  const int wid = tid >> 6, lane = tid & 63;
  const int wm = wid >> 1, wn = wid & 1;          // 2x2 wave grid, 64x64 each
  const int lrow = lane & 15;
  const int kq = lane >> 4;                       // 0..3
  const int sw = lrow & 7;                        // swizzle key
  const int m0 = blockIdx.y * 128;
  const int n0 = (EPI == 1) ? 0 : blockIdx.x * 128;
  int kbase = 0;
  if (EPI == 1) kbase = blockIdx.x * Kblk;
  if (EPI == 3) kbase = blockIdx.z * Kblk;

  f4_t acc[4][4];
#pragma unroll
  for (int i = 0; i < 4; ++i)
#pragma unroll
    for (int j = 0; j < 4; ++j) acc[i][j] = {0.f, 0.f, 0.f, 0.f};

  for (int kt = kbase; kt < kbase + Kblk; kt += 64) {
    stage64(A,  lda, m0, 0x3fffffff, kt, lsA, wid, lane);
    stage64(Bt, ldb, n0, Nact - 1,   kt, lsB, wid, lane);
    __syncthreads();
#pragma unroll
    for (int h = 0; h < 2; ++h) {
      const int lk = ((h * 4 + kq) ^ sw) * 8;
      bf8_t af[4], bfr[4];
#pragma unroll
      for (int mi = 0; mi < 4; ++mi)
        af[mi] = *(const bf8_t*)&lsA[(wm * 64 + mi * 16 + lrow) * 64 + lk];
#pragma unroll
      for (int ni = 0; ni < 4; ++ni)
        bfr[ni] = *(const bf8_t*)&lsB[(wn * 64 + ni * 16 + lrow) * 64 + lk];
#pragma unroll
      for (int mi = 0; mi < 4; ++mi)
#pragma unroll
        for (int ni = 0; ni < 4; ++ni)
          acc[mi][ni] = __builtin_amdgcn_mfma_f32_16x16x32_bf16(af[mi], bfr[ni], acc[mi][ni], 0, 0, 0);
    }
    __syncthreads();
  }

  const int rq = (lane >> 4) * 4;                  // C/D: row=(lane>>4)*4+r, col=lane&15
#pragma unroll
  for (int mi = 0; mi < 4; ++mi) {
#pragma unroll
    for (int ni = 0; ni < 4; ++ni) {
#pragma unroll
      for (int r = 0; r < 4; ++r) {
        int m = m0 + wm * 64 + mi * 16 + rq + r;
        int n = n0 + wn * 64 + ni * 16 + lrow;
        float v = acc[mi][ni][r];
        if (EPI == 0) {
          if (n < 2048) o16[(size_t)m * 2048 + n] = f2b(v);
          else          o16[(size_t)8388608 + (size_t)m * 2048 + (n - 2048)] = f2b(v);
        } else if (EPI == 1) {
          if (n < 96) of32[((size_t)blockIdx.x * 4096 + m) * 96 + n] = v;
        } else if (EPI == 2) {
          float t = v + biasf[n];
          float sp = (t > 20.f) ? t : log1pf(__expf(t));
          o16[(size_t)m * 2048 + n] = f2b(sp);
        } else {
          float* dst = blockIdx.z ? of32b : of32;
          dst[(size_t)m * 1024 + n] = v;
        }
      }
    }
  }
}

// distinct names per GEMM so rocprof ranks them individually
__global__ __launch_bounds__(256)
void gemm_in(const u16* A, int lda, const u16* Bt, int ldb, int Kblk, int Nact,
             u16* o16, float* of32, float* of32b, const float* biasf)
{ gemm_body<0>(A, lda, Bt, ldb, Kblk, Nact, o16, of32, of32b, biasf); }

__global__ __launch_bounds__(256)
void gemm_xp(const u16* A, int lda, const u16* Bt, int ldb, int Kblk, int Nact,
             u16* o16, float* of32, float* of32b, const float* biasf)
{ gemm_body<1>(A, lda, Bt, ldb, Kblk, Nact, o16, of32, of32b, biasf); }

__global__ __launch_bounds__(256)
void gemm_dt(const u16* A, int lda, const u16* Bt, int ldb, int Kblk, int Nact,
             u16* o16, float* of32, float* of32b, const float* biasf)
{ gemm_body<2>(A, lda, Bt, ldb, Kblk, Nact, o16, of32, of32b, biasf); }

__global__ __launch_bounds__(256)
void gemm_out(const u16* A, int lda, const u16* Bt, int ldb, int Kblk, int Nact,
              u16* o16, float* of32, float* of32b, const float* biasf)
{ gemm_body<3>(A, lda, Bt, ldb, Kblk, Nact, o16, of32, of32b, biasf); }

// reduce 8 split-K partials of x_proj; emit dtA bf16 [4096,64] + bc f32 [4096,32]
__global__ __launch_bounds__(256)
void xproj_reduce(const float* __restrict__ part, u16* __restrict__ dtA,
                  float* __restrict__ bc)
{
  int idx = blockIdx.x * 256 + threadIdx.x;   // 4096*96
  int m = idx / 96, n = idx - m * 96;
  float s = 0.f;
#pragma unroll
  for (int p = 0; p < 8; ++p) s += part[(size_t)p * 393216 + idx];
  if (n < 64) dtA[(size_t)m * 64 + n] = f2b(s);
  else        bc[(size_t)m * 32 + (n - 64)] = s;
}

// causal depthwise conv1d (window 4) + bias + silu; vectorized 8 channels/thread
__global__ __launch_bounds__(256)
void conv_silu(const u16* __restrict__ xib, const float* __restrict__ cw,
               const float* __restrict__ cb, u16* __restrict__ ub)
{
  int i = blockIdx.x * 256 + threadIdx.x;     // 1,048,576 threads
  int c8 = (i & 255) * 8;
  int row = i >> 8;                           // b*2048 + l
  int l = row & 2047;
  const u16* base = xib + (size_t)row * 2048 + c8;
  u16x8 x0 = {0,0,0,0,0,0,0,0}, x1 = x0, x2 = x0, x3;
  x3 = *(const u16x8*)(base);
  if (l >= 1) x2 = *(const u16x8*)(base - 2048);
  if (l >= 2) x1 = *(const u16x8*)(base - 2 * 2048);
  if (l >= 3) x0 = *(const u16x8*)(base - 3 * 2048);
  f4_t cb0 = *(const f4_t*)(cb + c8);
  f4_t cb1 = *(const f4_t*)(cb + c8 + 4);
  u16x8 o;
#pragma unroll
  for (int j = 0; j < 8; ++j) {
    f4_t w = *(const f4_t*)(cw + (size_t)(c8 + j) * 4);
    float a = (j < 4 ? cb0[j] : cb1[j - 4])
            + w[0] * b2f(x0[j]) + w[1] * b2f(x1[j])
            + w[2] * b2f(x2[j]) + w[3] * b2f(x3[j]);
    float s = a / (1.f + __expf(-a));
    o[j] = f2b(s);
  }
  *(u16x8*)(ub + (size_t)row * 2048 + c8) = o;
}

// ---- chunk-parallel scan, d-in-lane layout. 32 chunks x 64 steps. ----
// Structured-A fast path: reference A_log = log(arange(1..16)) broadcast,
// so Av[n] = (n+1)*Av[0] -> a_n = e1^(n+1), ONE exp + 15 muls per step.
// Runtime-checked per thread; generic fallback keeps correctness for any A.
__global__ __launch_bounds__(256)
void scan_s1(const u16* __restrict__ delta_bf, const u16* __restrict__ ub,
             const float* __restrict__ bc, const float* __restrict__ alog,
             float* __restrict__ P, float* __restrict__ Q)
{
  int blk = blockIdx.x;
  int g = blk & 7, c = (blk >> 3) & 31, b = blk >> 8;
  int d = g * 256 + threadIdx.x;
  float Av[16];
#pragma unroll
  for (int nq = 0; nq < 4; ++nq) {
    f4_t al = *(const f4_t*)(alog + (size_t)d * 16 + nq * 4);
#pragma unroll
    for (int j = 0; j < 4; ++j) Av[nq * 4 + j] = -__expf(al[j]);
  }
  float Av0 = Av[0];
  bool st = true;
#pragma unroll
  for (int n = 1; n < 16; ++n)
    st = st && (fabsf(Av[n] - (float)(n + 1) * Av0) <= 1e-3f * (float)(n + 1));
  f4_t Pr[4], Qr[4];
#pragma unroll
  for (int nq = 0; nq < 4; ++nq) { Pr[nq] = {1.f,1.f,1.f,1.f}; Qr[nq] = {0.f,0.f,0.f,0.f}; }
  int row0 = b * 2048 + c * 64;
  if (st) {
    for (int i = 0; i < 64; ++i) {
      size_t row = (size_t)(row0 + i);
      float dlt = b2f(delta_bf[row * 2048 + d]);
      float uv  = b2f(ub[row * 2048 + d]);
      const float* bp = bc + row * 32;
      f4_t Bv[4];
#pragma unroll
      for (int nq = 0; nq < 4; ++nq) Bv[nq] = *(const f4_t*)(bp + nq * 4);
      float du = dlt * uv;
      float e1 = __expf(dlt * Av0);
      float a = e1;
#pragma unroll
      for (int n = 0; n < 16; ++n) {
        Qr[n >> 2][n & 3] = a * Qr[n >> 2][n & 3] + du * Bv[n >> 2][n & 3];
        Pr[n >> 2][n & 3] *= a;
        a *= e1;
      }
    }
  } else {
    for (int i = 0; i < 64; ++i) {
      size_t row = (size_t)(row0 + i);
      float dlt = b2f(delta_bf[row * 2048 + d]);
      float uv  = b2f(ub[row * 2048 + d]);
      const float* bp = bc + row * 32;
      f4_t Bv[4];
#pragma unroll
      for (int nq = 0; nq < 4; ++nq) Bv[nq] = *(const f4_t*)(bp + nq * 4);
      float du = dlt * uv;
#pragma unroll
      for (int n = 0; n < 16; ++n) {
        float a = __expf(dlt * Av[n]);
        Qr[n >> 2][n & 3] = a * Qr[n >> 2][n & 3] + du * Bv[n >> 2][n & 3];
        Pr[n >> 2][n & 3] *= a;
      }
    }
  }
  size_t o = ((size_t)((b * 32 + c) * 2048 + d)) * 16;
#pragma unroll
  for (int nq = 0; nq < 4; ++nq) {
    *(f4_t*)(P + o + nq * 4) = Pr[nq];
    *(f4_t*)(Q + o + nq * 4) = Qr[nq];
  }
}

// S2: serial prefix over 32 chunks per (b,d,n); writes incoming-H into Q's slot.
__global__ __launch_bounds__(256)
void scan_comb(const float* __restrict__ P, float* __restrict__ Q)
{
  int idx = blockIdx.x * 256 + threadIdx.x;   // b*32768 + d*16+n
  int b = idx >> 15, dn = idx & 32767;
  size_t base = (size_t)b * 32 * 32768 + dn;
  float H = 0.f;
  for (int c = 0; c < 32; ++c) {
    size_t k = base + (size_t)c * 32768;
    float p = P[k], q = Q[k];
    Q[k] = H;
    H = p * H + q;
  }
}

// S3: re-scan with correct h_in; y = sum_n h*C in regs; fused D-skip + silu(z)
// gate; y overwrites z in place (coalesced bf16 stores). Structured-A fast exp.
__global__ __launch_bounds__(256)
void scan_s3(const u16* __restrict__ delta_bf, const u16* __restrict__ ub,
             const float* __restrict__ bc, const float* __restrict__ alog,
             const float* __restrict__ Q, const float* __restrict__ Dw,
             u16* __restrict__ zy)
{
  int blk = blockIdx.x;
  int g = blk & 7, c = (blk >> 3) & 31, b = blk >> 8;
  int d = g * 256 + threadIdx.x;
  float Av[16];
#pragma unroll
  for (int nq = 0; nq < 4; ++nq) {
    f4_t al = *(const f4_t*)(alog + (size_t)d * 16 + nq * 4);
#pragma unroll
    for (int j = 0; j < 4; ++j) Av[nq * 4 + j] = -__expf(al[j]);
  }
  float Av0 = Av[0];
  bool st = true;
#pragma unroll
  for (int n = 1; n < 16; ++n)
    st = st && (fabsf(Av[n] - (float)(n + 1) * Av0) <= 1e-3f * (float)(n + 1));
  f4_t h4[4];
  size_t o = ((size_t)((b * 32 + c) * 2048 + d)) * 16;
#pragma unroll
  for (int nq = 0; nq < 4; ++nq) h4[nq] = *(const f4_t*)(Q + o + nq * 4);
  float Dv = Dw[d];
  int row0 = b * 2048 + c * 64;
  if (st) {
    for (int i = 0; i < 64; ++i) {
      size_t row = (size_t)(row0 + i);
      float dlt = b2f(delta_bf[row * 2048 + d]);
      float uv  = b2f(ub[row * 2048 + d]);
      const float* bp = bc + row * 32;
      f4_t Bv[4], Cv[4];
#pragma unroll
      for (int nq = 0; nq < 4; ++nq) { Bv[nq] = *(const f4_t*)(bp + nq * 4); Cv[nq] = *(const f4_t*)(bp + 16 + nq * 4); }
      float du = dlt * uv;
      float e1 = __expf(dlt * Av0);
      float a = e1;
      float y = 0.f;
#pragma unroll
      for (int n = 0; n < 16; ++n) {
        float hn = a * h4[n >> 2][n & 3] + du * Bv[n >> 2][n & 3];
        h4[n >> 2][n & 3] = hn;
        y += hn * Cv[n >> 2][n & 3];
        a *= e1;
      }
      float zv = b2f(zy[row * 2048 + d]);
      float ov = (y + Dv * uv) * (zv / (1.f + __expf(-zv)));
      zy[row * 2048 + d] = f2b(ov);
    }
  } else {
    for (int i = 0; i < 64; ++i) {
      size_t row = (size_t)(row0 + i);
      float dlt = b2f(delta_bf[row * 2048 + d]);
      float uv  = b2f(ub[row * 2048 + d]);
      const float* bp = bc + row * 32;
      f4_t Bv[4], Cv[4];
#pragma unroll
      for (int nq = 0; nq < 4; ++nq) { Bv[nq] = *(const f4_t*)(bp + nq * 4); Cv[nq] = *(const f4_t*)(bp + 16 + nq * 4); }
      float du = dlt * uv;
      float y = 0.f;
#pragma unroll
      for (int n = 0; n < 16; ++n) {
        float a = __expf(dlt * Av[n]);
        float hn = a * h4[n >> 2][n & 3] + du * Bv[n >> 2][n & 3];
        h4[n >> 2][n & 3] = hn;
        y += hn * Cv[n >> 2][n & 3];
      }
      float zv = b2f(zy[row * 2048 + d]);
      float ov = (y + Dv * uv) * (zv / (1.f + __expf(-zv)));
      zy[row * 2048 + d] = f2b(ov);
    }
  }
}

// residual + LayerNorm over two out_proj partials, f32 in/out.
__global__ __launch_bounds__(256)
void ln_kernel(const float* __restrict__ hp0, const float* __restrict__ hp1,
               const float* __restrict__ xin,
               const float* __restrict__ lnw, const float* __restrict__ lnb,
               float* __restrict__ outp)
{
  __shared__ float ssum[4], ssq[4];
  int row = blockIdx.x, t = threadIdx.x;
  f4_t h0 = *(const f4_t*)(hp0 + (size_t)row * 1024 + t * 4);
  f4_t h1 = *(const f4_t*)(hp1 + (size_t)row * 1024 + t * 4);
  f4_t xv = *(const f4_t*)(xin + (size_t)row * 1024 + t * 4);
  float v[4], s = 0.f, q = 0.f;
#pragma unroll
  for (int j = 0; j < 4; ++j) { v[j] = h0[j] + h1[j] + xv[j]; s += v[j]; q += v[j] * v[j]; }
#pragma unroll
  for (int m = 32; m; m >>= 1) { s += __shfl_xor(s, m, 64); q += __shfl_xor(q, m, 64); }
  int wv = t >> 6;
  if ((t & 63) == 0) { ssum[wv] = s; ssq[wv] = q; }
  __syncthreads();
  s = ssum[0] + ssum[1] + ssum[2] + ssum[3];
  q = ssq[0] + ssq[1] + ssq[2] + ssq[3];
  float mu = s * (1.f / 1024.f);
  float var = q * (1.f / 1024.f) - mu * mu;
  float rs = rsqrtf(var + 1e-5f);
  f4_t o;
#pragma unroll
  for (int j = 0; j < 4; ++j)
    o[j] = (v[j] - mu) * rs * lnw[t * 4 + j] + lnb[t * 4 + j];
  *(f4_t*)(outp + (size_t)row * 1024 + t * 4) = o;
}

extern "C" void kernel_launch(void* const* d_in, const int* in_sizes, int n_in,
                              void* d_out, int out_size, void* d_ws, size_t ws_size,
                              hipStream_t stream)
{
  const float* x      = (const float*)d_in[0];   // [2,2048,1024]
  const float* inW    = (const float*)d_in[1];   // [4096,1024]
  const float* convW  = (const float*)d_in[2];   // [2048,1,4]
  const float* convB  = (const float*)d_in[3];   // [2048]
  const float* xprojW = (const float*)d_in[4];   // [96,2048]
  const float* dtW    = (const float*)d_in[5];   // [2048,64]
  const float* dtB    = (const float*)d_in[6];   // [2048]
  const float* alog   = (const float*)d_in[7];   // [2048,16]
  const float* Dw     = (const float*)d_in[8];   // [2048]
  const float* outW   = (const float*)d_in[9];   // [1024,2048]
  const float* lnw    = (const float*)d_in[10];  // [1024]
  const float* lnb    = (const float*)d_in[11];  // [1024]
  float* out = (float*)d_out;                    // [2,2048,1024] f32 (16 MiB)

  // Workspace (peak 56.23 MB, layout proven in rounds 6-8):
  //  [0,16M):            xi bf16 -> delta bf16 -> out_proj partial1 f32
  //  [16M,32M):          z bf16 -> y bf16 (scan_s3 in place)
  //  [32M,48M):          xb bf16 (8M) + inWb bf16 (8M) -> u bf16 (after gemm_in)
  //  [50331648,+512K):   dtA bf16 [4096,64]
  //  [50855936,+512K):   bc f32 [4096,32]
  //  [51380224,+384K):   xprojWb bf16 [96,2048]
  //  [51773440,+256K):   dtWb bf16 [2048,64]
  //  [52035584,+4M):     outWb bf16 [1024,2048]
  // d_out doubles as scratch: x_proj split-K partials (12.6 MB) -> P/Q (16 MB)
  // -> out_proj partial0 (16 MB) -> final output (ln reads then writes in place).
  char* ws = (char*)d_ws;
  u16*   xiz    = (u16*)(ws);
  u16*   zy     = xiz + 8388608;
  u16*   xb     = (u16*)(ws + 33554432);
  u16*   inWb   = xb + 4194304;
  u16*   u_bf   = (u16*)(ws + 33554432);          // overwrites xb/inWb after gemm_in
  u16*   dtA    = (u16*)(ws + 50331648);
  float* bc     = (float*)(ws + 50855936);
  u16*   xprojWb= (u16*)(ws + 51380224);
  u16*   dtWb   = (u16*)(ws + 51773440);
  u16*   outWb  = (u16*)(ws + 52035584);
  u16*   delta  = xiz;                            // overwrites dead xi
  float* hpart1 = (float*)(ws);                   // out_proj partial1 (delta dead)
  float* hpart0 = (float*)d_out;                  // out_proj partial0
  float* xpart  = (float*)d_out;                  // x_proj partials [8][4096][96]
  float* Pbuf   = (float*)d_out;
  float* Qbuf   = (float*)((char*)d_out + 8388608);

  dim3 blk(256);
  // fused f32 -> bf16 conversions (one launch)
  cvt_all<<<10560, blk, 0, stream>>>(x, inW, xprojW, dtW, outW,
                                     xb, inWb, xprojWb, dtWb, outWb);
  // in_proj: [4096,1024] x [4096,1024]^T -> xi | z (bf16)
  gemm_in<<<dim3(32, 32), blk, 0, stream>>>(xb, 1024, inWb, 1024, 1024, 4096, xiz, nullptr, nullptr, nullptr);
  // depthwise causal conv + silu -> u (bf16; overwrites xb/inWb)
  conv_silu<<<4096, blk, 0, stream>>>(xiz, convW, convB, u_bf);
  // x_proj split-K (8 x 256): partials into d_out
  gemm_xp<<<dim3(8, 32), blk, 0, stream>>>(u_bf, 2048, xprojWb, 2048, 256, 96, nullptr, xpart, nullptr, nullptr);
  xproj_reduce<<<1536, blk, 0, stream>>>(xpart, dtA, bc);
  // dt_proj + softplus -> delta (bf16, overwrites xi)
  gemm_dt<<<dim3(16, 32), blk, 0, stream>>>(dtA, 64, dtWb, 64, 64, 2048, delta, nullptr, nullptr, dtB);
  // chunk-parallel scan: S1 (P,q) -> combine -> S3 (y, gated, in place over z)
  scan_s1<<<512, blk, 0, stream>>>(delta, u_bf, bc, alog, Pbuf, Qbuf);
  scan_comb<<<256, blk, 0, stream>>>(Pbuf, Qbuf);
  scan_s3<<<512, blk, 0, stream>>>(delta, u_bf, bc, alog, Qbuf, Dw, zy);
  // out_proj split-K (2 x 1024): partial0 -> d_out, partial1 -> ws[0,16M)
  gemm_out<<<dim3(8, 32, 2), blk, 0, stream>>>(zy, 2048, outWb, 2048, 1024, 1024, nullptr, hpart0, hpart1, nullptr);
  // residual + LayerNorm (sums both partials) -> f32 out (in place over partial0)
  ln_kernel<<<4096, blk, 0, stream>>>(hpart0, hpart1, x, lnw, lnb, out);
}

// Round 10
// 333.398 us; speedup vs baseline: 5.3418x; 1.0176x over previous
//
#include <hip/hip_runtime.h>

typedef unsigned short u16;
typedef __attribute__((ext_vector_type(8))) short bf8_t;    // 8 x bf16 (4 VGPRs)
typedef __attribute__((ext_vector_type(4))) float f4_t;     // 4 x f32
typedef __attribute__((ext_vector_type(4))) unsigned short u16x4;
typedef __attribute__((ext_vector_type(8))) unsigned short u16x8;

__device__ __forceinline__ float b2f(u16 h) {
  union { unsigned u; float f; } v; v.u = ((unsigned)h) << 16; return v.f;
}
__device__ __forceinline__ u16 f2b(float f) {
  union { float f; unsigned u; } v; v.f = f;
  unsigned u = v.u;
  u += 0x7fffu + ((u >> 16) & 1u);   // round-nearest-even
  return (u16)(u >> 16);
}

#define AS1C(p) ((const __attribute__((address_space(1))) void*)(p))
#define AS3(p)  ((__attribute__((address_space(3))) void*)(p))

// one fused f32 -> bf16 convert over all 5 weight/input arrays
__global__ __launch_bounds__(256)
void cvt_all(const float* __restrict__ x, const float* __restrict__ inW,
             const float* __restrict__ xprojW, const float* __restrict__ dtW,
             const float* __restrict__ outW,
             u16* __restrict__ xb, u16* __restrict__ inWb, u16* __restrict__ xpb,
             u16* __restrict__ dtWb, u16* __restrict__ outWb)
{
  int i = blockIdx.x * 256 + threadIdx.x;      // float4 index, total 2703360
  if (i >= 2703360) return;
  const float* s; u16* d; int off;
  if (i < 1048576)      { s = x;      d = xb;    off = i; }
  else if (i < 2097152) { s = inW;    d = inWb;  off = i - 1048576; }
  else if (i < 2146304) { s = xprojW; d = xpb;   off = i - 2097152; }
  else if (i < 2179072) { s = dtW;    d = dtWb;  off = i - 2146304; }
  else                  { s = outW;   d = outWb; off = i - 2179072; }
  f4_t v = *(const f4_t*)(s + (size_t)off * 4);
  u16x4 o;
#pragma unroll
  for (int j = 0; j < 4; ++j) o[j] = f2b(v[j]);
  *(u16x4*)(d + (size_t)off * 4) = o;
}

// Stage one 128x64 bf16 tile (16 KB) into LDS, XOR-swizzled: granule (r,q)
// holds global colchunk q^(r&7). Staging lane i (chunk of 8 rows) fetches
// colchunk (i&7)^((i>>3)&7); reader uses granule (g ^ (row&7)). Bank-quad
// depends only on q_l -> 8 lanes per 4-bank group = 2/bank = conflict-free.
__device__ __forceinline__ void stage64(const u16* g, int ld, int row0, int rowmax,
                                        int k0, u16* lds, int wid, int lane) {
  int qg = (lane & 7) ^ ((lane >> 3) & 7);
#pragma unroll
  for (int c = 0; c < 4; ++c) {
    int chunk = wid * 4 + c;
    int r = row0 + chunk * 8 + (lane >> 3);
    if (r > rowmax) r = rowmax;                       // clamp (results discarded later)
    const u16* gp = g + (size_t)r * ld + k0 + qg * 8;
    __builtin_amdgcn_global_load_lds(AS1C(gp), AS3(lds + chunk * 512), 16, 0, 0);
  }
}

// C = A * Bt^T : A[M,K] bf16 row-major (lda), Bt[N,K] bf16 row-major (ldb).
// BK=64 (two 32-k half-steps per barrier epoch).
// EPI 0: in_proj  -> o16: n<2048 -> xi[m*2048+n]; else z at o16+8388608
// EPI 1: x_proj   -> split-K partials: of32[(bx*4096+m)*96+n], n<96
// EPI 2: dt_proj  -> o16[m*2048+n] = bf16(softplus(acc + biasf[n]))
// EPI 3: out_proj -> split-K: z=0 -> of32[m*1024+n], z=1 -> of32b[m*1024+n]
template<int EPI>
__device__ __forceinline__ void gemm_body(const u16* __restrict__ A, int lda,
             const u16* __restrict__ Bt, int ldb,
             int Kblk, int Nact,
             u16* __restrict__ o16, float* __restrict__ of32,
             float* __restrict__ of32b, const float* __restrict__ biasf)
{
  __shared__ u16 lsA[128 * 64];
  __shared__ u16 lsB[128 * 64];
  const int tid = threadIdx.x;
  const int wid = tid >> 6, lane = tid & 63;
  const int wm = wid >> 1, wn = wid & 1;          // 2x2 wave grid, 64x64 each
  const int lrow = lane & 15;
  const int kq = lane >> 4;                       // 0..3
  const int sw = lrow & 7;                        // swizzle key
  const int m0 = blockIdx.y * 128;
  const int n0 = (EPI == 1) ? 0 : blockIdx.x * 128;
  int kbase = 0;
  if (EPI == 1) kbase = blockIdx.x * Kblk;
  if (EPI == 3) kbase = blockIdx.z * Kblk;

  f4_t acc[4][4];
#pragma unroll
  for (int i = 0; i < 4; ++i)
#pragma unroll
    for (int j = 0; j < 4; ++j) acc[i][j] = {0.f, 0.f, 0.f, 0.f};

  for (int kt = kbase; kt < kbase + Kblk; kt += 64) {
    stage64(A,  lda, m0, 0x3fffffff, kt, lsA, wid, lane);
    stage64(Bt, ldb, n0, Nact - 1,   kt, lsB, wid, lane);
    __syncthreads();
#pragma unroll
    for (int h = 0; h < 2; ++h) {
      const int lk = ((h * 4 + kq) ^ sw) * 8;
      bf8_t af[4], bfr[4];
#pragma unroll
      for (int mi = 0; mi < 4; ++mi)
        af[mi] = *(const bf8_t*)&lsA[(wm * 64 + mi * 16 + lrow) * 64 + lk];
#pragma unroll
      for (int ni = 0; ni < 4; ++ni)
        bfr[ni] = *(const bf8_t*)&lsB[(wn * 64 + ni * 16 + lrow) * 64 + lk];
#pragma unroll
      for (int mi = 0; mi < 4; ++mi)
#pragma unroll
        for (int ni = 0; ni < 4; ++ni)
          acc[mi][ni] = __builtin_amdgcn_mfma_f32_16x16x32_bf16(af[mi], bfr[ni], acc[mi][ni], 0, 0, 0);
    }
    __syncthreads();
  }

  const int rq = (lane >> 4) * 4;                  // C/D: row=(lane>>4)*4+r, col=lane&15
#pragma unroll
  for (int mi = 0; mi < 4; ++mi) {
#pragma unroll
    for (int ni = 0; ni < 4; ++ni) {
#pragma unroll
      for (int r = 0; r < 4; ++r) {
        int m = m0 + wm * 64 + mi * 16 + rq + r;
        int n = n0 + wn * 64 + ni * 16 + lrow;
        float v = acc[mi][ni][r];
        if (EPI == 0) {
          if (n < 2048) o16[(size_t)m * 2048 + n] = f2b(v);
          else          o16[(size_t)8388608 + (size_t)m * 2048 + (n - 2048)] = f2b(v);
        } else if (EPI == 1) {
          if (n < 96) of32[((size_t)blockIdx.x * 4096 + m) * 96 + n] = v;
        } else if (EPI == 2) {
          float t = v + biasf[n];
          float sp = (t > 20.f) ? t : log1pf(__expf(t));
          o16[(size_t)m * 2048 + n] = f2b(sp);
        } else {
          float* dst = blockIdx.z ? of32b : of32;
          dst[(size_t)m * 1024 + n] = v;
        }
      }
    }
  }
}

// distinct names per GEMM so rocprof ranks them individually
__global__ __launch_bounds__(256)
void gemm_in(const u16* A, int lda, const u16* Bt, int ldb, int Kblk, int Nact,
             u16* o16, float* of32, float* of32b, const float* biasf)
{ gemm_body<0>(A, lda, Bt, ldb, Kblk, Nact, o16, of32, of32b, biasf); }

__global__ __launch_bounds__(256)
void gemm_xp(const u16* A, int lda, const u16* Bt, int ldb, int Kblk, int Nact,
             u16* o16, float* of32, float* of32b, const float* biasf)
{ gemm_body<1>(A, lda, Bt, ldb, Kblk, Nact, o16, of32, of32b, biasf); }

__global__ __launch_bounds__(256)
void gemm_dt(const u16* A, int lda, const u16* Bt, int ldb, int Kblk, int Nact,
             u16* o16, float* of32, float* of32b, const float* biasf)
{ gemm_body<2>(A, lda, Bt, ldb, Kblk, Nact, o16, of32, of32b, biasf); }

__global__ __launch_bounds__(256)
void gemm_out(const u16* A, int lda, const u16* Bt, int ldb, int Kblk, int Nact,
              u16* o16, float* of32, float* of32b, const float* biasf)
{ gemm_body<3>(A, lda, Bt, ldb, Kblk, Nact, o16, of32, of32b, biasf); }

// reduce 8 split-K partials of x_proj; emit dtA bf16 [4096,64] + bc f32 [4096,32]
__global__ __launch_bounds__(256)
void xproj_reduce(const float* __restrict__ part, u16* __restrict__ dtA,
                  float* __restrict__ bc)
{
  int idx = blockIdx.x * 256 + threadIdx.x;   // 4096*96
  int m = idx / 96, n = idx - m * 96;
  float s = 0.f;
#pragma unroll
  for (int p = 0; p < 8; ++p) s += part[(size_t)p * 393216 + idx];
  if (n < 64) dtA[(size_t)m * 64 + n] = f2b(s);
  else        bc[(size_t)m * 32 + (n - 64)] = s;
}

// causal depthwise conv1d (window 4) + bias + silu; vectorized 8 channels/thread
__global__ __launch_bounds__(256)
void conv_silu(const u16* __restrict__ xib, const float* __restrict__ cw,
               const float* __restrict__ cb, u16* __restrict__ ub)
{
  int i = blockIdx.x * 256 + threadIdx.x;     // 1,048,576 threads
  int c8 = (i & 255) * 8;
  int row = i >> 8;                           // b*2048 + l
  int l = row & 2047;
  const u16* base = xib + (size_t)row * 2048 + c8;
  u16x8 x0 = {0,0,0,0,0,0,0,0}, x1 = x0, x2 = x0, x3;
  x3 = *(const u16x8*)(base);
  if (l >= 1) x2 = *(const u16x8*)(base - 2048);
  if (l >= 2) x1 = *(const u16x8*)(base - 2 * 2048);
  if (l >= 3) x0 = *(const u16x8*)(base - 3 * 2048);
  f4_t cb0 = *(const f4_t*)(cb + c8);
  f4_t cb1 = *(const f4_t*)(cb + c8 + 4);
  u16x8 o;
#pragma unroll
  for (int j = 0; j < 8; ++j) {
    f4_t w = *(const f4_t*)(cw + (size_t)(c8 + j) * 4);
    float a = (j < 4 ? cb0[j] : cb1[j - 4])
            + w[0] * b2f(x0[j]) + w[1] * b2f(x1[j])
            + w[2] * b2f(x2[j]) + w[3] * b2f(x3[j]);
    float s = a / (1.f + __expf(-a));
    o[j] = f2b(s);
  }
  *(u16x8*)(ub + (size_t)row * 2048 + c8) = o;
}

// ---- chunk-parallel scan, d-in-lane layout. 32 chunks x 64 steps. ----
// Key identity: P[n] = prod_i exp(dlt_i*Av[n]) = exp(Av[n] * sum_i dlt_i),
// so s1 stores only S = sum(dlt) (1 f32 per (b,c,d)) + Q[16] — P is never
// materialized; comb reconstructs p = exp(Av*S) on the fly.
// Structured-A fast path (A_log = log(arange(1..16)) broadcast): one exp +
// 15 muls per step for the a-chain. Runtime-checked; generic fallback.
__global__ __launch_bounds__(256)
void scan_s1(const u16* __restrict__ delta_bf, const u16* __restrict__ ub,
             const float* __restrict__ bc, const float* __restrict__ alog,
             float* __restrict__ S, float* __restrict__ Q)
{
  int blk = blockIdx.x;
  int g = blk & 7, c = (blk >> 3) & 31, b = blk >> 8;
  int d = g * 256 + threadIdx.x;
  float Av[16];
#pragma unroll
  for (int nq = 0; nq < 4; ++nq) {
    f4_t al = *(const f4_t*)(alog + (size_t)d * 16 + nq * 4);
#pragma unroll
    for (int j = 0; j < 4; ++j) Av[nq * 4 + j] = -__expf(al[j]);
  }
  float Av0 = Av[0];
  bool st = true;
#pragma unroll
  for (int n = 1; n < 16; ++n)
    st = st && (fabsf(Av[n] - (float)(n + 1) * Av0) <= 1e-3f * (float)(n + 1));
  f4_t Qr[4];
#pragma unroll
  for (int nq = 0; nq < 4; ++nq) Qr[nq] = {0.f,0.f,0.f,0.f};
  float Sd = 0.f;
  int row0 = b * 2048 + c * 64;
  if (st) {
    for (int i = 0; i < 64; ++i) {
      size_t row = (size_t)(row0 + i);
      float dlt = b2f(delta_bf[row * 2048 + d]);
      float uv  = b2f(ub[row * 2048 + d]);
      const float* bp = bc + row * 32;
      f4_t Bv[4];
#pragma unroll
      for (int nq = 0; nq < 4; ++nq) Bv[nq] = *(const f4_t*)(bp + nq * 4);
      float du = dlt * uv;
      float e1 = __expf(dlt * Av0);
      float a = e1;
      Sd += dlt;
#pragma unroll
      for (int n = 0; n < 16; ++n) {
        Qr[n >> 2][n & 3] = a * Qr[n >> 2][n & 3] + du * Bv[n >> 2][n & 3];
        a *= e1;
      }
    }
  } else {
    for (int i = 0; i < 64; ++i) {
      size_t row = (size_t)(row0 + i);
      float dlt = b2f(delta_bf[row * 2048 + d]);
      float uv  = b2f(ub[row * 2048 + d]);
      const float* bp = bc + row * 32;
      f4_t Bv[4];
#pragma unroll
      for (int nq = 0; nq < 4; ++nq) Bv[nq] = *(const f4_t*)(bp + nq * 4);
      float du = dlt * uv;
      Sd += dlt;
#pragma unroll
      for (int n = 0; n < 16; ++n) {
        float a = __expf(dlt * Av[n]);
        Qr[n >> 2][n & 3] = a * Qr[n >> 2][n & 3] + du * Bv[n >> 2][n & 3];
      }
    }
  }
  S[(size_t)(b * 32 + c) * 2048 + d] = Sd;
  size_t o = ((size_t)((b * 32 + c) * 2048 + d)) * 16;
#pragma unroll
  for (int nq = 0; nq < 4; ++nq)
    *(f4_t*)(Q + o + nq * 4) = Qr[nq];
}

// S2: serial prefix over 32 chunks per (b,d,n); p = exp(Av[n]*S) recomputed;
// writes incoming-H into Q's slot.
__global__ __launch_bounds__(256)
void scan_comb(const float* __restrict__ S, float* __restrict__ Q,
               const float* __restrict__ alog)
{
  int idx = blockIdx.x * 256 + threadIdx.x;   // b*32768 + d*16+n
  int b = idx >> 15, dn = idx & 32767;
  int d = dn >> 4;
  float Av = -__expf(alog[dn]);
  size_t base = (size_t)b * 1048576 + dn;
  float H = 0.f;
  for (int c = 0; c < 32; ++c) {
    size_t k = base + (size_t)c * 32768;
    float Sv = S[(size_t)(b * 32 + c) * 2048 + d];
    float q = Q[k];
    Q[k] = H;
    H = __expf(Av * Sv) * H + q;
  }
}

// S3: re-scan with correct h_in; y = sum_n h*C in regs; fused D-skip + silu(z)
// gate; y overwrites z in place (coalesced bf16 stores). Structured-A fast exp.
__global__ __launch_bounds__(256)
void scan_s3(const u16* __restrict__ delta_bf, const u16* __restrict__ ub,
             const float* __restrict__ bc, const float* __restrict__ alog,
             const float* __restrict__ Q, const float* __restrict__ Dw,
             u16* __restrict__ zy)
{
  int blk = blockIdx.x;
  int g = blk & 7, c = (blk >> 3) & 31, b = blk >> 8;
  int d = g * 256 + threadIdx.x;
  float Av[16];
#pragma unroll
  for (int nq = 0; nq < 4; ++nq) {
    f4_t al = *(const f4_t*)(alog + (size_t)d * 16 + nq * 4);
#pragma unroll
    for (int j = 0; j < 4; ++j) Av[nq * 4 + j] = -__expf(al[j]);
  }
  float Av0 = Av[0];
  bool st = true;
#pragma unroll
  for (int n = 1; n < 16; ++n)
    st = st && (fabsf(Av[n] - (float)(n + 1) * Av0) <= 1e-3f * (float)(n + 1));
  f4_t h4[4];
  size_t o = ((size_t)((b * 32 + c) * 2048 + d)) * 16;
#pragma unroll
  for (int nq = 0; nq < 4; ++nq) h4[nq] = *(const f4_t*)(Q + o + nq * 4);
  float Dv = Dw[d];
  int row0 = b * 2048 + c * 64;
  if (st) {
    for (int i = 0; i < 64; ++i) {
      size_t row = (size_t)(row0 + i);
      float dlt = b2f(delta_bf[row * 2048 + d]);
      float uv  = b2f(ub[row * 2048 + d]);
      const float* bp = bc + row * 32;
      f4_t Bv[4], Cv[4];
#pragma unroll
      for (int nq = 0; nq < 4; ++nq) { Bv[nq] = *(const f4_t*)(bp + nq * 4); Cv[nq] = *(const f4_t*)(bp + 16 + nq * 4); }
      float du = dlt * uv;
      float e1 = __expf(dlt * Av0);
      float a = e1;
      float y = 0.f;
#pragma unroll
      for (int n = 0; n < 16; ++n) {
        float hn = a * h4[n >> 2][n & 3] + du * Bv[n >> 2][n & 3];
        h4[n >> 2][n & 3] = hn;
        y += hn * Cv[n >> 2][n & 3];
        a *= e1;
      }
      float zv = b2f(zy[row * 2048 + d]);
      float ov = (y + Dv * uv) * (zv / (1.f + __expf(-zv)));
      zy[row * 2048 + d] = f2b(ov);
    }
  } else {
    for (int i = 0; i < 64; ++i) {
      size_t row = (size_t)(row0 + i);
      float dlt = b2f(delta_bf[row * 2048 + d]);
      float uv  = b2f(ub[row * 2048 + d]);
      const float* bp = bc + row * 32;
      f4_t Bv[4], Cv[4];
#pragma unroll
      for (int nq = 0; nq < 4; ++nq) { Bv[nq] = *(const f4_t*)(bp + nq * 4); Cv[nq] = *(const f4_t*)(bp + 16 + nq * 4); }
      float du = dlt * uv;
      float y = 0.f;
#pragma unroll
      for (int n = 0; n < 16; ++n) {
        float a = __expf(dlt * Av[n]);
        float hn = a * h4[n >> 2][n & 3] + du * Bv[n >> 2][n & 3];
        h4[n >> 2][n & 3] = hn;
        y += hn * Cv[n >> 2][n & 3];
      }
      float zv = b2f(zy[row * 2048 + d]);
      float ov = (y + Dv * uv) * (zv / (1.f + __expf(-zv)));
      zy[row * 2048 + d] = f2b(ov);
    }
  }
}

// residual + LayerNorm over two out_proj partials, f32 in/out.
__global__ __launch_bounds__(256)
void ln_kernel(const float* __restrict__ hp0, const float* __restrict__ hp1,
               const float* __restrict__ xin,
               const float* __restrict__ lnw, const float* __restrict__ lnb,
               float* __restrict__ outp)
{
  __shared__ float ssum[4], ssq[4];
  int row = blockIdx.x, t = threadIdx.x;
  f4_t h0 = *(const f4_t*)(hp0 + (size_t)row * 1024 + t * 4);
  f4_t h1 = *(const f4_t*)(hp1 + (size_t)row * 1024 + t * 4);
  f4_t xv = *(const f4_t*)(xin + (size_t)row * 1024 + t * 4);
  float v[4], s = 0.f, q = 0.f;
#pragma unroll
  for (int j = 0; j < 4; ++j) { v[j] = h0[j] + h1[j] + xv[j]; s += v[j]; q += v[j] * v[j]; }
#pragma unroll
  for (int m = 32; m; m >>= 1) { s += __shfl_xor(s, m, 64); q += __shfl_xor(q, m, 64); }
  int wv = t >> 6;
  if ((t & 63) == 0) { ssum[wv] = s; ssq[wv] = q; }
  __syncthreads();
  s = ssum[0] + ssum[1] + ssum[2] + ssum[3];
  q = ssq[0] + ssq[1] + ssq[2] + ssq[3];
  float mu = s * (1.f / 1024.f);
  float var = q * (1.f / 1024.f) - mu * mu;
  float rs = rsqrtf(var + 1e-5f);
  f4_t o;
#pragma unroll
  for (int j = 0; j < 4; ++j)
    o[j] = (v[j] - mu) * rs * lnw[t * 4 + j] + lnb[t * 4 + j];
  *(f4_t*)(outp + (size_t)row * 1024 + t * 4) = o;
}

extern "C" void kernel_launch(void* const* d_in, const int* in_sizes, int n_in,
                              void* d_out, int out_size, void* d_ws, size_t ws_size,
                              hipStream_t stream)
{
  const float* x      = (const float*)d_in[0];   // [2,2048,1024]
  const float* inW    = (const float*)d_in[1];   // [4096,1024]
  const float* convW  = (const float*)d_in[2];   // [2048,1,4]
  const float* convB  = (const float*)d_in[3];   // [2048]
  const float* xprojW = (const float*)d_in[4];   // [96,2048]
  const float* dtW    = (const float*)d_in[5];   // [2048,64]
  const float* dtB    = (const float*)d_in[6];   // [2048]
  const float* alog   = (const float*)d_in[7];   // [2048,16]
  const float* Dw     = (const float*)d_in[8];   // [2048]
  const float* outW   = (const float*)d_in[9];   // [1024,2048]
  const float* lnw    = (const float*)d_in[10];  // [1024]
  const float* lnb    = (const float*)d_in[11];  // [1024]
  float* out = (float*)d_out;                    // [2,2048,1024] f32 (16 MiB)

  // Workspace (peak ~53.6 MiB, layout proven in rounds 6-9):
  //  [0,16M):            xi bf16 -> delta bf16 -> out_proj partial1 f32
  //  [16M,32M):          z bf16 -> y bf16 (scan_s3 in place)
  //  [32M,48M):          xb bf16 (8M) + inWb bf16 (8M) -> u bf16 (after gemm_in)
  //  [50331648,+512K):   dtA bf16 [4096,64]
  //  [50855936,+512K):   bc f32 [4096,32]
  //  [51380224,+384K):   xprojWb bf16 [96,2048]
  //  [51773440,+256K):   dtWb bf16 [2048,64]
  //  [52035584,+4M):     outWb bf16 [1024,2048]
  // d_out doubles as scratch: x_proj split-K partials (12.6 MB) -> S (512 KB @0)
  // + Q (8.4 MB @8M) -> out_proj partial0 (16 MB) -> final output (in place).
  char* ws = (char*)d_ws;
  u16*   xiz    = (u16*)(ws);
  u16*   zy     = xiz + 8388608;
  u16*   xb     = (u16*)(ws + 33554432);
  u16*   inWb   = xb + 4194304;
  u16*   u_bf   = (u16*)(ws + 33554432);          // overwrites xb/inWb after gemm_in
  u16*   dtA    = (u16*)(ws + 50331648);
  float* bc     = (float*)(ws + 50855936);
  u16*   xprojWb= (u16*)(ws + 51380224);
  u16*   dtWb   = (u16*)(ws + 51773440);
  u16*   outWb  = (u16*)(ws + 52035584);
  u16*   delta  = xiz;                            // overwrites dead xi
  float* hpart1 = (float*)(ws);                   // out_proj partial1 (delta dead)
  float* hpart0 = (float*)d_out;                  // out_proj partial0
  float* xpart  = (float*)d_out;                  // x_proj partials [8][4096][96]
  float* Sbuf   = (float*)d_out;                  // chunk delta-sums [2][32][2048]
  float* Qbuf   = (float*)((char*)d_out + 8388608);

  dim3 blk(256);
  // fused f32 -> bf16 conversions (one launch)
  cvt_all<<<10560, blk, 0, stream>>>(x, inW, xprojW, dtW, outW,
                                     xb, inWb, xprojWb, dtWb, outWb);
  // in_proj: [4096,1024] x [4096,1024]^T -> xi | z (bf16)
  gemm_in<<<dim3(32, 32), blk, 0, stream>>>(xb, 1024, inWb, 1024, 1024, 4096, xiz, nullptr, nullptr, nullptr);
  // depthwise causal conv + silu -> u (bf16; overwrites xb/inWb)
  conv_silu<<<4096, blk, 0, stream>>>(xiz, convW, convB, u_bf);
  // x_proj split-K (8 x 256): partials into d_out
  gemm_xp<<<dim3(8, 32), blk, 0, stream>>>(u_bf, 2048, xprojWb, 2048, 256, 96, nullptr, xpart, nullptr, nullptr);
  xproj_reduce<<<1536, blk, 0, stream>>>(xpart, dtA, bc);
  // dt_proj + softplus -> delta (bf16, overwrites xi)
  gemm_dt<<<dim3(16, 32), blk, 0, stream>>>(dtA, 64, dtWb, 64, 64, 2048, delta, nullptr, nullptr, dtB);
  // chunk-parallel scan: S1 (S,Q) -> combine (p=exp(Av*S)) -> S3 (gated y)
  scan_s1<<<512, blk, 0, stream>>>(delta, u_bf, bc, alog, Sbuf, Qbuf);
  scan_comb<<<256, blk, 0, stream>>>(Sbuf, Qbuf, alog);
  scan_s3<<<512, blk, 0, stream>>>(delta, u_bf, bc, alog, Qbuf, Dw, zy);
  // out_proj split-K (2 x 1024): partial0 -> d_out, partial1 -> ws[0,16M)
  gemm_out<<<dim3(8, 32, 2), blk, 0, stream>>>(zy, 2048, outWb, 2048, 1024, 1024, nullptr, hpart0, hpart1, nullptr);
  // residual + LayerNorm (sums both partials) -> f32 out (in place over partial0)
  ln_kernel<<<4096, blk, 0, stream>>>(hpart0, hpart1, x, lnw, lnb, out);
}

// Round 11
// 327.627 us; speedup vs baseline: 5.4359x; 1.0176x over previous
//
#include <hip/hip_runtime.h>

typedef unsigned short u16;
typedef __attribute__((ext_vector_type(8))) short bf8_t;    // 8 x bf16 (4 VGPRs)
typedef __attribute__((ext_vector_type(4))) float f4_t;     // 4 x f32
typedef __attribute__((ext_vector_type(4))) unsigned short u16x4;
typedef __attribute__((ext_vector_type(8))) unsigned short u16x8;

__device__ __forceinline__ float b2f(u16 h) {
  union { unsigned u; float f; } v; v.u = ((unsigned)h) << 16; return v.f;
}
__device__ __forceinline__ u16 f2b(float f) {
  union { float f; unsigned u; } v; v.f = f;
  unsigned u = v.u;
  u += 0x7fffu + ((u >> 16) & 1u);   // round-nearest-even
  return (u16)(u >> 16);
}

#define AS1C(p) ((const __attribute__((address_space(1))) void*)(p))
#define AS3(p)  ((__attribute__((address_space(3))) void*)(p))

// one fused f32 -> bf16 convert over all 5 weight/input arrays
__global__ __launch_bounds__(256)
void cvt_all(const float* __restrict__ x, const float* __restrict__ inW,
             const float* __restrict__ xprojW, const float* __restrict__ dtW,
             const float* __restrict__ outW,
             u16* __restrict__ xb, u16* __restrict__ inWb, u16* __restrict__ xpb,
             u16* __restrict__ dtWb, u16* __restrict__ outWb)
{
  int i = blockIdx.x * 256 + threadIdx.x;      // float4 index, total 2703360
  if (i >= 2703360) return;
  const float* s; u16* d; int off;
  if (i < 1048576)      { s = x;      d = xb;    off = i; }
  else if (i < 2097152) { s = inW;    d = inWb;  off = i - 1048576; }
  else if (i < 2146304) { s = xprojW; d = xpb;   off = i - 2097152; }
  else if (i < 2179072) { s = dtW;    d = dtWb;  off = i - 2146304; }
  else                  { s = outW;   d = outWb; off = i - 2179072; }
  f4_t v = *(const f4_t*)(s + (size_t)off * 4);
  u16x4 o;
#pragma unroll
  for (int j = 0; j < 4; ++j) o[j] = f2b(v[j]);
  *(u16x4*)(d + (size_t)off * 4) = o;
}

// Stage one 128x64 bf16 tile (16 KB) into LDS, XOR-swizzled: granule (r,q)
// holds global colchunk q^(r&7). Staging lane i (chunk of 8 rows) fetches
// colchunk (i&7)^((i>>3)&7); reader uses granule (g ^ (row&7)). Bank-quad
// depends only on q_l -> 8 lanes per 4-bank group = 2/bank = conflict-free.
__device__ __forceinline__ void stage64(const u16* g, int ld, int row0, int rowmax,
                                        int k0, u16* lds, int wid, int lane) {
  int qg = (lane & 7) ^ ((lane >> 3) & 7);
#pragma unroll
  for (int c = 0; c < 4; ++c) {
    int chunk = wid * 4 + c;
    int r = row0 + chunk * 8 + (lane >> 3);
    if (r > rowmax) r = rowmax;                       // clamp (results discarded later)
    const u16* gp = g + (size_t)r * ld + k0 + qg * 8;
    __builtin_amdgcn_global_load_lds(AS1C(gp), AS3(lds + chunk * 512), 16, 0, 0);
  }
}

// C = A * Bt^T : A[M,K] bf16 row-major (lda), Bt[N,K] bf16 row-major (ldb).
// BK=64 (two 32-k half-steps per barrier epoch).
// EPI 0: in_proj  -> o16: n<2048 -> xi[m*2048+n]; else z at o16+8388608
// EPI 1: x_proj   -> split-K partials: of32[(bx*4096+m)*96+n], n<96
// EPI 2: dt_proj  -> o16[m*2048+n] = bf16(softplus(acc + biasf[n]))
// EPI 3: out_proj -> split-K: z=0 -> of32[m*1024+n], z=1 -> of32b[m*1024+n]
template<int EPI>
__device__ __forceinline__ void gemm_body(const u16* __restrict__ A, int lda,
             const u16* __restrict__ Bt, int ldb,
             int Kblk, int Nact,
             u16* __restrict__ o16, float* __restrict__ of32,
             float* __restrict__ of32b, const float* __restrict__ biasf)
{
  __shared__ u16 lsA[128 * 64];
  __shared__ u16 lsB[128 * 64];
  const int tid = threadIdx.x;
  const int wid = tid >> 6, lane = tid & 63;
  const int wm = wid >> 1, wn = wid & 1;          // 2x2 wave grid, 64x64 each
  const int lrow = lane & 15;
  const int kq = lane >> 4;                       // 0..3
  const int sw = lrow & 7;                        // swizzle key
  const int m0 = blockIdx.y * 128;
  const int n0 = (EPI == 1) ? 0 : blockIdx.x * 128;
  int kbase = 0;
  if (EPI == 1) kbase = blockIdx.x * Kblk;
  if (EPI == 3) kbase = blockIdx.z * Kblk;

  f4_t acc[4][4];
#pragma unroll
  for (int i = 0; i < 4; ++i)
#pragma unroll
    for (int j = 0; j < 4; ++j) acc[i][j] = {0.f, 0.f, 0.f, 0.f};

  for (int kt = kbase; kt < kbase + Kblk; kt += 64) {
    stage64(A,  lda, m0, 0x3fffffff, kt, lsA, wid, lane);
    stage64(Bt, ldb, n0, Nact - 1,   kt, lsB, wid, lane);
    __syncthreads();
#pragma unroll
    for (int h = 0; h < 2; ++h) {
      const int lk = ((h * 4 + kq) ^ sw) * 8;
      bf8_t af[4], bfr[4];
#pragma unroll
      for (int mi = 0; mi < 4; ++mi)
        af[mi] = *(const bf8_t*)&lsA[(wm * 64 + mi * 16 + lrow) * 64 + lk];
#pragma unroll
      for (int ni = 0; ni < 4; ++ni)
        bfr[ni] = *(const bf8_t*)&lsB[(wn * 64 + ni * 16 + lrow) * 64 + lk];
#pragma unroll
      for (int mi = 0; mi < 4; ++mi)
#pragma unroll
        for (int ni = 0; ni < 4; ++ni)
          acc[mi][ni] = __builtin_amdgcn_mfma_f32_16x16x32_bf16(af[mi], bfr[ni], acc[mi][ni], 0, 0, 0);
    }
    __syncthreads();
  }

  const int rq = (lane >> 4) * 4;                  // C/D: row=(lane>>4)*4+r, col=lane&15
#pragma unroll
  for (int mi = 0; mi < 4; ++mi) {
#pragma unroll
    for (int ni = 0; ni < 4; ++ni) {
#pragma unroll
      for (int r = 0; r < 4; ++r) {
        int m = m0 + wm * 64 + mi * 16 + rq + r;
        int n = n0 + wn * 64 + ni * 16 + lrow;
        float v = acc[mi][ni][r];
        if (EPI == 0) {
          if (n < 2048) o16[(size_t)m * 2048 + n] = f2b(v);
          else          o16[(size_t)8388608 + (size_t)m * 2048 + (n - 2048)] = f2b(v);
        } else if (EPI == 1) {
          if (n < 96) of32[((size_t)blockIdx.x * 4096 + m) * 96 + n] = v;
        } else if (EPI == 2) {
          float t = v + biasf[n];
          float sp = (t > 20.f) ? t : log1pf(__expf(t));
          o16[(size_t)m * 2048 + n] = f2b(sp);
        } else {
          float* dst = blockIdx.z ? of32b : of32;
          dst[(size_t)m * 1024 + n] = v;
        }
      }
    }
  }
}

// distinct names per GEMM so rocprof ranks them individually
__global__ __launch_bounds__(256)
void gemm_in(const u16* A, int lda, const u16* Bt, int ldb, int Kblk, int Nact,
             u16* o16, float* of32, float* of32b, const float* biasf)
{ gemm_body<0>(A, lda, Bt, ldb, Kblk, Nact, o16, of32, of32b, biasf); }

__global__ __launch_bounds__(256)
void gemm_xp(const u16* A, int lda, const u16* Bt, int ldb, int Kblk, int Nact,
             u16* o16, float* of32, float* of32b, const float* biasf)
{ gemm_body<1>(A, lda, Bt, ldb, Kblk, Nact, o16, of32, of32b, biasf); }

__global__ __launch_bounds__(256)
void gemm_dt(const u16* A, int lda, const u16* Bt, int ldb, int Kblk, int Nact,
             u16* o16, float* of32, float* of32b, const float* biasf)
{ gemm_body<2>(A, lda, Bt, ldb, Kblk, Nact, o16, of32, of32b, biasf); }

__global__ __launch_bounds__(256)
void gemm_out(const u16* A, int lda, const u16* Bt, int ldb, int Kblk, int Nact,
              u16* o16, float* of32, float* of32b, const float* biasf)
{ gemm_body<3>(A, lda, Bt, ldb, Kblk, Nact, o16, of32, of32b, biasf); }

// reduce 8 split-K partials of x_proj; emit dtA bf16 [4096,64] + bc f32 [4096,32]
__global__ __launch_bounds__(256)
void xproj_reduce(const float* __restrict__ part, u16* __restrict__ dtA,
                  float* __restrict__ bc)
{
  int idx = blockIdx.x * 256 + threadIdx.x;   // 4096*96
  int m = idx / 96, n = idx - m * 96;
  float s = 0.f;
#pragma unroll
  for (int p = 0; p < 8; ++p) s += part[(size_t)p * 393216 + idx];
  if (n < 64) dtA[(size_t)m * 64 + n] = f2b(s);
  else        bc[(size_t)m * 32 + (n - 64)] = s;
}

// causal depthwise conv1d (window 4) + bias + silu; vectorized 8 channels/thread
__global__ __launch_bounds__(256)
void conv_silu(const u16* __restrict__ xib, const float* __restrict__ cw,
               const float* __restrict__ cb, u16* __restrict__ ub)
{
  int i = blockIdx.x * 256 + threadIdx.x;     // 1,048,576 threads
  int c8 = (i & 255) * 8;
  int row = i >> 8;                           // b*2048 + l
  int l = row & 2047;
  const u16* base = xib + (size_t)row * 2048 + c8;
  u16x8 x0 = {0,0,0,0,0,0,0,0}, x1 = x0, x2 = x0, x3;
  x3 = *(const u16x8*)(base);
  if (l >= 1) x2 = *(const u16x8*)(base - 2048);
  if (l >= 2) x1 = *(const u16x8*)(base - 2 * 2048);
  if (l >= 3) x0 = *(const u16x8*)(base - 3 * 2048);
  f4_t cb0 = *(const f4_t*)(cb + c8);
  f4_t cb1 = *(const f4_t*)(cb + c8 + 4);
  u16x8 o;
#pragma unroll
  for (int j = 0; j < 8; ++j) {
    f4_t w = *(const f4_t*)(cw + (size_t)(c8 + j) * 4);
    float a = (j < 4 ? cb0[j] : cb1[j - 4])
            + w[0] * b2f(x0[j]) + w[1] * b2f(x1[j])
            + w[2] * b2f(x2[j]) + w[3] * b2f(x3[j]);
    float s = a / (1.f + __expf(-a));
    o[j] = f2b(s);
  }
  *(u16x8*)(ub + (size_t)row * 2048 + c8) = o;
}

// ---- chunk-parallel scan, d-in-lane layout. 64 chunks x 32 steps. ----
// (4 blocks/CU -> 16 waves/CU for latency hiding; was 2 blocks/CU at 32 chunks)
// P[n] = exp(Av[n] * sum(dlt)) — only S = sum(dlt) stored (bf16, dtA slot).
// Q (from-zero chunk states, f32) fills d_out exactly (16.78 MB).
// Structured-A fast path: one exp + 15 muls per step; runtime-checked.
__global__ __launch_bounds__(256)
void scan_s1(const u16* __restrict__ delta_bf, const u16* __restrict__ ub,
             const float* __restrict__ bc, const float* __restrict__ alog,
             u16* __restrict__ S, float* __restrict__ Q)
{
  int blk = blockIdx.x;                // 1024 blocks: b(1) x c(6) x g(3)
  int g = blk & 7, c = (blk >> 3) & 63, b = blk >> 9;
  int d = g * 256 + threadIdx.x;
  float Av[16];
#pragma unroll
  for (int nq = 0; nq < 4; ++nq) {
    f4_t al = *(const f4_t*)(alog + (size_t)d * 16 + nq * 4);
#pragma unroll
    for (int j = 0; j < 4; ++j) Av[nq * 4 + j] = -__expf(al[j]);
  }
  float Av0 = Av[0];
  bool st = true;
#pragma unroll
  for (int n = 1; n < 16; ++n)
    st = st && (fabsf(Av[n] - (float)(n + 1) * Av0) <= 1e-3f * (float)(n + 1));
  f4_t Qr[4];
#pragma unroll
  for (int nq = 0; nq < 4; ++nq) Qr[nq] = {0.f,0.f,0.f,0.f};
  float Sd = 0.f;
  int row0 = b * 2048 + c * 32;
  if (st) {
#pragma unroll 2
    for (int i = 0; i < 32; ++i) {
      size_t row = (size_t)(row0 + i);
      float dlt = b2f(delta_bf[row * 2048 + d]);
      float uv  = b2f(ub[row * 2048 + d]);
      const float* bp = bc + row * 32;
      f4_t Bv[4];
#pragma unroll
      for (int nq = 0; nq < 4; ++nq) Bv[nq] = *(const f4_t*)(bp + nq * 4);
      float du = dlt * uv;
      float e1 = __expf(dlt * Av0);
      float a = e1;
      Sd += dlt;
#pragma unroll
      for (int n = 0; n < 16; ++n) {
        Qr[n >> 2][n & 3] = a * Qr[n >> 2][n & 3] + du * Bv[n >> 2][n & 3];
        a *= e1;
      }
    }
  } else {
#pragma unroll 2
    for (int i = 0; i < 32; ++i) {
      size_t row = (size_t)(row0 + i);
      float dlt = b2f(delta_bf[row * 2048 + d]);
      float uv  = b2f(ub[row * 2048 + d]);
      const float* bp = bc + row * 32;
      f4_t Bv[4];
#pragma unroll
      for (int nq = 0; nq < 4; ++nq) Bv[nq] = *(const f4_t*)(bp + nq * 4);
      float du = dlt * uv;
      Sd += dlt;
#pragma unroll
      for (int n = 0; n < 16; ++n) {
        float a = __expf(dlt * Av[n]);
        Qr[n >> 2][n & 3] = a * Qr[n >> 2][n & 3] + du * Bv[n >> 2][n & 3];
      }
    }
  }
  S[(size_t)(b * 64 + c) * 2048 + d] = f2b(Sd);
  size_t o = ((size_t)((b * 64 + c) * 2048 + d)) * 16;
#pragma unroll
  for (int nq = 0; nq < 4; ++nq)
    *(f4_t*)(Q + o + nq * 4) = Qr[nq];
}

// S2: serial prefix over 64 chunks per (b,d,n); p = exp(Av[n]*S) recomputed;
// grouped prefetch (16 loads in flight) hides latency; H into Q's slot.
__global__ __launch_bounds__(256)
void scan_comb(const u16* __restrict__ S16, float* __restrict__ Q,
               const float* __restrict__ alog)
{
  int idx = blockIdx.x * 256 + threadIdx.x;   // b*32768 + d*16+n
  int b = idx >> 15, dn = idx & 32767;
  int d = dn >> 4;
  float Av = -__expf(alog[dn]);
  size_t qbase = (size_t)b * 2097152 + dn;
  size_t sbase = (size_t)b * 131072 + d;
  float H = 0.f;
#pragma unroll
  for (int cg = 0; cg < 4; ++cg) {
    float sv[16], qv[16];
#pragma unroll
    for (int j = 0; j < 16; ++j) {
      int c = cg * 16 + j;
      qv[j] = Q[qbase + (size_t)c * 32768];
      sv[j] = b2f(S16[sbase + (size_t)c * 2048]);
    }
#pragma unroll
    for (int j = 0; j < 16; ++j) {
      int c = cg * 16 + j;
      Q[qbase + (size_t)c * 32768] = H;
      H = __expf(Av * sv[j]) * H + qv[j];
    }
  }
}

// S3: re-scan with correct h_in; y = sum_n h*C in regs; fused D-skip + silu(z)
// gate; y overwrites z in place (coalesced bf16 stores). Structured-A fast exp.
__global__ __launch_bounds__(256)
void scan_s3(const u16* __restrict__ delta_bf, const u16* __restrict__ ub,
             const float* __restrict__ bc, const float* __restrict__ alog,
             const float* __restrict__ Q, const float* __restrict__ Dw,
             u16* __restrict__ zy)
{
  int blk = blockIdx.x;                // 1024 blocks
  int g = blk & 7, c = (blk >> 3) & 63, b = blk >> 9;
  int d = g * 256 + threadIdx.x;
  float Av[16];
#pragma unroll
  for (int nq = 0; nq < 4; ++nq) {
    f4_t al = *(const f4_t*)(alog + (size_t)d * 16 + nq * 4);
#pragma unroll
    for (int j = 0; j < 4; ++j) Av[nq * 4 + j] = -__expf(al[j]);
  }
  float Av0 = Av[0];
  bool st = true;
#pragma unroll
  for (int n = 1; n < 16; ++n)
    st = st && (fabsf(Av[n] - (float)(n + 1) * Av0) <= 1e-3f * (float)(n + 1));
  f4_t h4[4];
  size_t o = ((size_t)((b * 64 + c) * 2048 + d)) * 16;
#pragma unroll
  for (int nq = 0; nq < 4; ++nq) h4[nq] = *(const f4_t*)(Q + o + nq * 4);
  float Dv = Dw[d];
  int row0 = b * 2048 + c * 32;
  if (st) {
#pragma unroll 2
    for (int i = 0; i < 32; ++i) {
      size_t row = (size_t)(row0 + i);
      float dlt = b2f(delta_bf[row * 2048 + d]);
      float uv  = b2f(ub[row * 2048 + d]);
      const float* bp = bc + row * 32;
      f4_t Bv[4], Cv[4];
#pragma unroll
      for (int nq = 0; nq < 4; ++nq) { Bv[nq] = *(const f4_t*)(bp + nq * 4); Cv[nq] = *(const f4_t*)(bp + 16 + nq * 4); }
      float du = dlt * uv;
      float e1 = __expf(dlt * Av0);
      float a = e1;
      float y = 0.f;
#pragma unroll
      for (int n = 0; n < 16; ++n) {
        float hn = a * h4[n >> 2][n & 3] + du * Bv[n >> 2][n & 3];
        h4[n >> 2][n & 3] = hn;
        y += hn * Cv[n >> 2][n & 3];
        a *= e1;
      }
      float zv = b2f(zy[row * 2048 + d]);
      float ov = (y + Dv * uv) * (zv / (1.f + __expf(-zv)));
      zy[row * 2048 + d] = f2b(ov);
    }
  } else {
#pragma unroll 2
    for (int i = 0; i < 32; ++i) {
      size_t row = (size_t)(row0 + i);
      float dlt = b2f(delta_bf[row * 2048 + d]);
      float uv  = b2f(ub[row * 2048 + d]);
      const float* bp = bc + row * 32;
      f4_t Bv[4], Cv[4];
#pragma unroll
      for (int nq = 0; nq < 4; ++nq) { Bv[nq] = *(const f4_t*)(bp + nq * 4); Cv[nq] = *(const f4_t*)(bp + 16 + nq * 4); }
      float du = dlt * uv;
      float y = 0.f;
#pragma unroll
      for (int n = 0; n < 16; ++n) {
        float a = __expf(dlt * Av[n]);
        float hn = a * h4[n >> 2][n & 3] + du * Bv[n >> 2][n & 3];
        h4[n >> 2][n & 3] = hn;
        y += hn * Cv[n >> 2][n & 3];
      }
      float zv = b2f(zy[row * 2048 + d]);
      float ov = (y + Dv * uv) * (zv / (1.f + __expf(-zv)));
      zy[row * 2048 + d] = f2b(ov);
    }
  }
}

// residual + LayerNorm over two out_proj partials, f32 in/out.
__global__ __launch_bounds__(256)
void ln_kernel(const float* __restrict__ hp0, const float* __restrict__ hp1,
               const float* __restrict__ xin,
               const float* __restrict__ lnw, const float* __restrict__ lnb,
               float* __restrict__ outp)
{
  __shared__ float ssum[4], ssq[4];
  int row = blockIdx.x, t = threadIdx.x;
  f4_t h0 = *(const f4_t*)(hp0 + (size_t)row * 1024 + t * 4);
  f4_t h1 = *(const f4_t*)(hp1 + (size_t)row * 1024 + t * 4);
  f4_t xv = *(const f4_t*)(xin + (size_t)row * 1024 + t * 4);
  float v[4], s = 0.f, q = 0.f;
#pragma unroll
  for (int j = 0; j < 4; ++j) { v[j] = h0[j] + h1[j] + xv[j]; s += v[j]; q += v[j] * v[j]; }
#pragma unroll
  for (int m = 32; m; m >>= 1) { s += __shfl_xor(s, m, 64); q += __shfl_xor(q, m, 64); }
  int wv = t >> 6;
  if ((t & 63) == 0) { ssum[wv] = s; ssq[wv] = q; }
  __syncthreads();
  s = ssum[0] + ssum[1] + ssum[2] + ssum[3];
  q = ssq[0] + ssq[1] + ssq[2] + ssq[3];
  float mu = s * (1.f / 1024.f);
  float var = q * (1.f / 1024.f) - mu * mu;
  float rs = rsqrtf(var + 1e-5f);
  f4_t o;
#pragma unroll
  for (int j = 0; j < 4; ++j)
    o[j] = (v[j] - mu) * rs * lnw[t * 4 + j] + lnb[t * 4 + j];
  *(f4_t*)(outp + (size_t)row * 1024 + t * 4) = o;
}

extern "C" void kernel_launch(void* const* d_in, const int* in_sizes, int n_in,
                              void* d_out, int out_size, void* d_ws, size_t ws_size,
                              hipStream_t stream)
{
  const float* x      = (const float*)d_in[0];   // [2,2048,1024]
  const float* inW    = (const float*)d_in[1];   // [4096,1024]
  const float* convW  = (const float*)d_in[2];   // [2048,1,4]
  const float* convB  = (const float*)d_in[3];   // [2048]
  const float* xprojW = (const float*)d_in[4];   // [96,2048]
  const float* dtW    = (const float*)d_in[5];   // [2048,64]
  const float* dtB    = (const float*)d_in[6];   // [2048]
  const float* alog   = (const float*)d_in[7];   // [2048,16]
  const float* Dw     = (const float*)d_in[8];   // [2048]
  const float* outW   = (const float*)d_in[9];   // [1024,2048]
  const float* lnw    = (const float*)d_in[10];  // [1024]
  const float* lnb    = (const float*)d_in[11];  // [1024]
  float* out = (float*)d_out;                    // [2,2048,1024] f32 (16 MiB)

  // Workspace (peak ~56.23 MB, layout proven rounds 6-10):
  //  [0,16M):            xi bf16 -> delta bf16 -> out_proj partial1 f32
  //  [16M,32M):          z bf16 -> y bf16 (scan_s3 in place)
  //  [32M,48M):          xb bf16 (8M) + inWb bf16 (8M) -> u bf16 (after gemm_in)
  //  [50331648,+512K):   dtA bf16 [4096,64] -> S bf16 [2,64,2048] (after gemm_dt)
  //  [50855936,+512K):   bc f32 [4096,32]
  //  [51380224,+384K):   xprojWb bf16 [96,2048]
  //  [51773440,+256K):   dtWb bf16 [2048,64]
  //  [52035584,+4M):     outWb bf16 [1024,2048]
  // d_out doubles as scratch: x_proj split-K partials (12.6 MB) -> Q f32
  // [2,64,2048,16] (16.78 MB, exact fit) -> out_proj partial0 -> final output.
  char* ws = (char*)d_ws;
  u16*   xiz    = (u16*)(ws);
  u16*   zy     = xiz + 8388608;
  u16*   xb     = (u16*)(ws + 33554432);
  u16*   inWb   = xb + 4194304;
  u16*   u_bf   = (u16*)(ws + 33554432);          // overwrites xb/inWb after gemm_in
  u16*   dtA    = (u16*)(ws + 50331648);
  float* bc     = (float*)(ws + 50855936);
  u16*   xprojWb= (u16*)(ws + 51380224);
  u16*   dtWb   = (u16*)(ws + 51773440);
  u16*   outWb  = (u16*)(ws + 52035584);
  u16*   delta  = xiz;                            // overwrites dead xi
  float* hpart1 = (float*)(ws);                   // out_proj partial1 (delta dead)
  float* hpart0 = (float*)d_out;                  // out_proj partial0
  float* xpart  = (float*)d_out;                  // x_proj partials [8][4096][96]
  u16*   Sbuf   = dtA;                            // S (dtA dead after gemm_dt)
  float* Qbuf   = (float*)d_out;                  // Q fills d_out exactly

  dim3 blk(256);
  // fused f32 -> bf16 conversions (one launch)
  cvt_all<<<10560, blk, 0, stream>>>(x, inW, xprojW, dtW, outW,
                                     xb, inWb, xprojWb, dtWb, outWb);
  // in_proj: [4096,1024] x [4096,1024]^T -> xi | z (bf16)
  gemm_in<<<dim3(32, 32), blk, 0, stream>>>(xb, 1024, inWb, 1024, 1024, 4096, xiz, nullptr, nullptr, nullptr);
  // depthwise causal conv + silu -> u (bf16; overwrites xb/inWb)
  conv_silu<<<4096, blk, 0, stream>>>(xiz, convW, convB, u_bf);
  // x_proj split-K (8 x 256): partials into d_out
  gemm_xp<<<dim3(8, 32), blk, 0, stream>>>(u_bf, 2048, xprojWb, 2048, 256, 96, nullptr, xpart, nullptr, nullptr);
  xproj_reduce<<<1536, blk, 0, stream>>>(xpart, dtA, bc);
  // dt_proj + softplus -> delta (bf16, overwrites xi)
  gemm_dt<<<dim3(16, 32), blk, 0, stream>>>(dtA, 64, dtWb, 64, 64, 2048, delta, nullptr, nullptr, dtB);
  // chunk-parallel scan (64 chunks x 32 steps): S1 -> combine -> S3
  scan_s1<<<1024, blk, 0, stream>>>(delta, u_bf, bc, alog, Sbuf, Qbuf);
  scan_comb<<<256, blk, 0, stream>>>(Sbuf, Qbuf, alog);
  scan_s3<<<1024, blk, 0, stream>>>(delta, u_bf, bc, alog, Qbuf, Dw, zy);
  // out_proj split-K (2 x 1024): partial0 -> d_out, partial1 -> ws[0,16M)
  gemm_out<<<dim3(8, 32, 2), blk, 0, stream>>>(zy, 2048, outWb, 2048, 1024, 1024, nullptr, hpart0, hpart1, nullptr);
  // residual + LayerNorm (sums both partials) -> f32 out (in place over partial0)
  ln_kernel<<<4096, blk, 0, stream>>>(hpart0, hpart1, x, lnw, lnb, out);
}